// Round 9
// baseline (199.068 us; speedup 1.0000x reference)
//
#include <hip/hip_runtime.h>

// CAM (channel attention): x [16,512,64,64] fp32, gamma scalar.
// energy[b] = Q Q^T; att = softmax(rowmax - energy) == exp(rowmin-e)/sum;
// out = gamma*(att@Q) + x.
// Fast path: fp16 MFMA GEMMs, BK=32, 40KB-class LDS -> 4 blocks/CU (32
// waves/CU) for cross-block pipe overlap.
//   gram: symmetric (10 tiles), 128x128, K-split {4,2,1} by ws tier,
//         2-buffer drain loop; epilogue via 2x half LDS transpose + mirror.
//   pv:   128x128, A 2-buf + B 3-buf counted vmcnt(1) (never 0 mid-loop),
//         setprio, Qh fp16 residual; epilogue via half LDS transpose.
// Swizzle for 64B rows: chunk ^ ((row>>1)&3) (2-way max = free).
// XCD-aware bijective block swizzle everywhere. Fallback: fp32 path.

constexpr int Bb = 16;
constexpr int Cc = 512;
constexpr int NN = 4096;  // 64*64

typedef _Float16 half8 __attribute__((ext_vector_type(8)));
typedef _Float16 half4 __attribute__((ext_vector_type(4)));
typedef float float4v __attribute__((ext_vector_type(4)));

// ---------------------------------------------------------------------------
__device__ inline void gld_lds16(const _Float16* g, _Float16* l) {
    __builtin_amdgcn_global_load_lds(
        (const __attribute__((address_space(1))) unsigned int*)g,
        (__attribute__((address_space(3))) unsigned int*)l, 16, 0, 0);
}

// ---------------------------------------------------------------------------
// Prep: x fp32 [b][512 d][4096 n] -> Qh fp16 [b][d][n] and QhT fp16 [b][n][d].
__global__ __launch_bounds__(256) void prep_kernel(const float* __restrict__ x,
                                                   _Float16* __restrict__ Qh,
                                                   _Float16* __restrict__ QhT) {
    __shared__ float T[64][65];
    const int b = blockIdx.z;
    const int n0 = blockIdx.x * 64;
    const int d0 = blockIdx.y * 64;
    const float* xb = x + ((size_t)b * Cc + d0) * NN + n0;
    const int tid = threadIdx.x;
#pragma unroll
    for (int i = 0; i < 4; ++i) {
        int lin = tid + i * 256;
        int dr = lin >> 4;
        int c4 = (lin & 15) * 4;
        float4 v = *reinterpret_cast<const float4*>(&xb[(size_t)dr * NN + c4]);
        T[dr][c4 + 0] = v.x; T[dr][c4 + 1] = v.y;
        T[dr][c4 + 2] = v.z; T[dr][c4 + 3] = v.w;
    }
    __syncthreads();
#pragma unroll
    for (int i = 0; i < 2; ++i) {
        int widx = tid + i * 256;
        int dr = widx >> 3;
        int cn = widx & 7;
        half8 h;
#pragma unroll
        for (int j = 0; j < 8; ++j) h[j] = (_Float16)T[dr][cn * 8 + j];
        size_t dst = ((size_t)b * Cc + d0 + dr) * NN + n0 + cn * 8;
        *reinterpret_cast<half8*>(&Qh[dst]) = h;
    }
#pragma unroll
    for (int i = 0; i < 2; ++i) {
        int widx = tid + i * 256;
        int nr = widx >> 3;
        int cd = widx & 7;
        half8 h;
#pragma unroll
        for (int j = 0; j < 8; ++j) h[j] = (_Float16)T[cd * 8 + j][nr];
        size_t dst = ((size_t)b * NN + n0 + nr) * Cc + d0 + cd * 8;
        *reinterpret_cast<half8*>(&QhT[dst]) = h;
    }
}

// ---------------------------------------------------------------------------
// Symmetric gram: energy = Qh Qh^T, upper-triangle tiles (10 of 16), mirror
// via half-LDS transpose. 128x128 tile, BK=32, 8 waves (2x4, each 64x32),
// 2-buffer drain loop, 4 blocks/CU. K-split SPLIT; grid = 10*SPLIT*Bb.
template <int SPLIT>
__global__ __launch_bounds__(512, 8) void gram_sym(const _Float16* __restrict__ A,
                                                   float* __restrict__ D) {
    constexpr int NT = 128 / SPLIT;                // K-tiles of 32 halves
    __shared__ __align__(16) float gL[64 * 132];   // 33792 B; aliases staging
    _Float16* sAB = (_Float16*)gL;                 // sA[2]|sB[2] = 32768 B
    const int BPB = 10 * SPLIT;
    const int L = blockIdx.x;
    const int t0 = (L & 7) * ((BPB * Bb) >> 3) + (L >> 3);
    const int b = t0 / BPB;
    const int rem = t0 % BPB;
    const int ti = rem / SPLIT;
    const int half = rem % SPLIT;
    const int kBase = half * NT * 32;
    float* Deff = D + (size_t)half * Bb * Cc * Cc;
    int tr, tc;
    if (ti < 4)      { tr = 0; tc = ti; }
    else if (ti < 7) { tr = 1; tc = ti - 3; }
    else if (ti < 9) { tr = 2; tc = ti - 5; }
    else             { tr = 3; tc = 3; }
    const int rowTile = tr * 128;
    const int colTile = tc * 128;

    const _Float16* Ab = A + (size_t)b * Cc * NN;
    const int tid = threadIdx.x;

    float4v acc[4][2];
#pragma unroll
    for (int m = 0; m < 4; ++m)
#pragma unroll
        for (int n = 0; n < 2; ++n) acc[m][n] = (float4v){0.f, 0.f, 0.f, 0.f};

    // One BK=32 tile pair; 1 A-load + 1 B-load per lane.
    auto stage = [&](int buf, int kt) {
        const int k0 = kBase + (kt << 5);
        _Float16* sA = sAB + buf * 4096;
        _Float16* sB = sAB + 8192 + buf * 4096;
        int r = tid >> 2, c = tid & 3;
        int cs = (c ^ ((r >> 1) & 3)) << 3;
        gld_lds16(Ab + (size_t)(rowTile + r) * NN + k0 + cs, sA + tid * 8);
        gld_lds16(Ab + (size_t)(colTile + r) * NN + k0 + cs, sB + tid * 8);
    };

    stage(0, 0);
    __syncthreads();

    const int wid = tid >> 6, lane = tid & 63;
    const int wr = wid >> 2, wc = wid & 3;   // 2 x 4 waves, each 64(m) x 32(n)
    const int lr = lane & 15, q = lane >> 4;

    for (int t = 0; t < NT; ++t) {
        if (t + 1 < NT) stage((t + 1) & 1, t + 1);
        const _Float16* cA = sAB + (t & 1) * 4096;
        const _Float16* cB = sAB + 8192 + (t & 1) * 4096;
        half8 af[4], bf[2];
#pragma unroll
        for (int m = 0; m < 4; ++m) {
            int r = wr * 64 + m * 16 + lr;
            int c = q ^ ((r >> 1) & 3);
            af[m] = *reinterpret_cast<const half8*>(&cA[r * 32 + c * 8]);
        }
#pragma unroll
        for (int n = 0; n < 2; ++n) {
            int r = wc * 32 + n * 16 + lr;
            int c = q ^ ((r >> 1) & 3);
            bf[n] = *reinterpret_cast<const half8*>(&cB[r * 32 + c * 8]);
        }
        __builtin_amdgcn_s_setprio(1);
#pragma unroll
        for (int m = 0; m < 4; ++m)
#pragma unroll
            for (int n = 0; n < 2; ++n)
                acc[m][n] = __builtin_amdgcn_mfma_f32_16x16x32_f16(af[m], bf[n], acc[m][n], 0, 0, 0);
        __builtin_amdgcn_s_setprio(0);
        __syncthreads();
    }

    // Epilogue: two 64-row half-passes through padded LDS (+ mirror).
    float* Db = Deff + (size_t)b * Cc * Cc;
#pragma unroll
    for (int h = 0; h < 2; ++h) {
        __syncthreads();
        if (wr == h) {
#pragma unroll
            for (int m = 0; m < 4; ++m)
#pragma unroll
                for (int n = 0; n < 2; ++n)
#pragma unroll
                    for (int e = 0; e < 4; ++e)
                        gL[(m * 16 + q * 4 + e) * 132 + wc * 32 + n * 16 + lr] = acc[m][n][e];
        }
        __syncthreads();
#pragma unroll
        for (int k = 0; k < 4; ++k) {
            int c2 = tid + k * 512;
            int row = c2 >> 5;
            int col = (c2 & 31) << 2;
            float4 v = *reinterpret_cast<const float4*>(&gL[row * 132 + col]);
            *reinterpret_cast<float4*>(&Db[(size_t)(rowTile + h * 64 + row) * Cc + colTile + col]) = v;
        }
        if (tr != tc) {
#pragma unroll
            for (int k = 0; k < 4; ++k) {
                int c2 = tid + k * 512;
                int crow = c2 >> 4;
                int r4 = (c2 & 15) << 2;
                float4 v;
                v.x = gL[(r4 + 0) * 132 + crow];
                v.y = gL[(r4 + 1) * 132 + crow];
                v.z = gL[(r4 + 2) * 132 + crow];
                v.w = gL[(r4 + 3) * 132 + crow];
                *reinterpret_cast<float4*>(&Db[(size_t)(colTile + crow) * Cc + rowTile + h * 64 + r4]) = v;
            }
        }
    }
}

// ---------------------------------------------------------------------------
// PV: out = gamma*(attH @ QhT^T) + residual. 128x128 tile, BK=32, 8 waves.
// A 2-buf + B 3-buf = 40 KB -> 4 blocks/CU. Counted vmcnt(1) steady state.
// RES=0: residual from x (fp32); RES=1: residual from Qh (fp16).
template <int RES>
__global__ __launch_bounds__(512, 8) void pv_mfma(const _Float16* __restrict__ A,
                                                  const _Float16* __restrict__ Bp,
                                                  const float* __restrict__ xres,
                                                  const _Float16* __restrict__ Qh,
                                                  const float* __restrict__ gamma,
                                                  float* __restrict__ out) {
    __shared__ __align__(16) _Float16 smem[5 * 4096];  // sA[2]|sB[3] = 40 KB
    float* L = (float*)smem;                           // epilogue view 33792 B
    const int BPB = 128;
    const int Lb = blockIdx.x;
    const int t0 = (Lb & 7) * ((BPB * Bb) >> 3) + (Lb >> 3);
    const int b = t0 / BPB;
    const int rem = t0 % BPB;
    const int rowTile = (rem & 3) * 128;   // attH row panel (L2-hot)
    const int colTile = (rem >> 2) * 128;  // QhT panel (compulsory-only)

    const _Float16* Ab = A + (size_t)b * Cc * Cc;    // attH [512][512]
    const _Float16* Bbp = Bp + (size_t)b * NN * Cc;  // QhT  [4096][512]
    const int tid = threadIdx.x;

    float4v acc[4][2];
#pragma unroll
    for (int m = 0; m < 4; ++m)
#pragma unroll
        for (int n = 0; n < 2; ++n) acc[m][n] = (float4v){0.f, 0.f, 0.f, 0.f};

    // 1 load/lane per stage call (vmcnt ledger unit = 1).
    auto stageA = [&](_Float16* dst, int kt) {
        const int k0 = kt << 5;
        int r = tid >> 2, c = tid & 3;
        int cs = (c ^ ((r >> 1) & 3)) << 3;
        gld_lds16(Ab + (size_t)(rowTile + r) * Cc + k0 + cs, dst + tid * 8);
    };
    auto stageB = [&](_Float16* dst, int kt) {
        const int k0 = kt << 5;
        int r = tid >> 2, c = tid & 3;
        int cs = (c ^ ((r >> 1) & 3)) << 3;
        gld_lds16(Bbp + (size_t)(colTile + r) * Cc + k0 + cs, dst + tid * 8);
    };

    _Float16* sA0 = smem;
    _Float16* sA1 = smem + 4096;
    _Float16* sB_ = smem + 8192;  // 3 x 4096

    // Prologue queue: [A0(1), B0(1), B1(1)]
    stageA(sA0, 0);
    stageB(sB_, 0);
    stageB(sB_ + 4096, 1);

    const int wid = tid >> 6, lane = tid & 63;
    const int wr = wid >> 2, wc = wid & 3;   // 2 x 4 waves, each 64(m) x 32(n)
    const int lr = lane & 15, q = lane >> 4;

#pragma unroll
    for (int t = 0; t < 16; ++t) {
        // Need A(t),B(t) done; newest allowed in flight = B(t+1).
        if (t < 15) asm volatile("s_waitcnt vmcnt(1)" ::: "memory");
        else        asm volatile("s_waitcnt vmcnt(0)" ::: "memory");
        __builtin_amdgcn_s_barrier();
        __builtin_amdgcn_sched_barrier(0);

        const _Float16* cA = (t & 1) ? sA1 : sA0;
        const _Float16* cB = sB_ + (t % 3) * 4096;
        half8 af[4], bf[2];
#pragma unroll
        for (int m = 0; m < 4; ++m) {
            int r = wr * 64 + m * 16 + lr;
            int c = q ^ ((r >> 1) & 3);
            af[m] = *reinterpret_cast<const half8*>(&cA[r * 32 + c * 8]);
        }
#pragma unroll
        for (int n = 0; n < 2; ++n) {
            int r = wc * 32 + n * 16 + lr;
            int c = q ^ ((r >> 1) & 3);
            bf[n] = *reinterpret_cast<const half8*>(&cB[r * 32 + c * 8]);
        }
        if (t + 1 < 16) stageA((t & 1) ? sA0 : sA1, t + 1);
        if (t + 2 < 16) stageB(sB_ + ((t + 2) % 3) * 4096, t + 2);

        __builtin_amdgcn_s_setprio(1);
#pragma unroll
        for (int m = 0; m < 4; ++m)
#pragma unroll
            for (int n = 0; n < 2; ++n)
                acc[m][n] = __builtin_amdgcn_mfma_f32_16x16x32_f16(af[m], bf[n], acc[m][n], 0, 0, 0);
        __builtin_amdgcn_s_setprio(0);
    }

    // Epilogue: two 64-row half-passes through padded LDS, residual + store.
    const float g = gamma[0];
    const size_t base = (size_t)b * Cc * NN;
#pragma unroll
    for (int h = 0; h < 2; ++h) {
        __syncthreads();
        if (wr == h) {
#pragma unroll
            for (int m = 0; m < 4; ++m)
#pragma unroll
                for (int n = 0; n < 2; ++n)
#pragma unroll
                    for (int e = 0; e < 4; ++e)
                        L[(m * 16 + q * 4 + e) * 132 + wc * 32 + n * 16 + lr] = acc[m][n][e];
        }
        __syncthreads();
#pragma unroll
        for (int k = 0; k < 4; ++k) {
            int c2 = tid + k * 512;
            int row = c2 >> 5;
            int col = (c2 & 31) << 2;
            float4 v = *reinterpret_cast<const float4*>(&L[row * 132 + col]);
            size_t o = base + (size_t)(rowTile + h * 64 + row) * NN + colTile + col;
            float4 ov;
            if (RES == 0) {
                float4 xi = *reinterpret_cast<const float4*>(&xres[o]);
                ov.x = fmaf(g, v.x, xi.x); ov.y = fmaf(g, v.y, xi.y);
                ov.z = fmaf(g, v.z, xi.z); ov.w = fmaf(g, v.w, xi.w);
            } else {
                half4 hq = *reinterpret_cast<const half4*>(&Qh[o]);
                ov.x = fmaf(g, v.x, (float)hq[0]); ov.y = fmaf(g, v.y, (float)hq[1]);
                ov.z = fmaf(g, v.z, (float)hq[2]); ov.w = fmaf(g, v.w, (float)hq[3]);
            }
            *reinterpret_cast<float4*>(&out[o]) = ov;
        }
    }
}

// ---------------------------------------------------------------------------
// Softmax: att = exp(rowmin - e)/sum over HALVES partial-energy buffers
// (each Bb*Cc*Cc floats, summed); fp16 att out (plain row-major).
template <int HALVES>
__global__ __launch_bounds__(256) void softmax_fp16(const float* __restrict__ eA,
                                                    _Float16* __restrict__ attH) {
    const size_t NE = (size_t)Bb * Cc * Cc;
    const int wave = threadIdx.x >> 6;
    const int lane = threadIdx.x & 63;
    const int row = blockIdx.x * 4 + wave;
    float v[8];
    {
        const float* E1 = eA + (size_t)row * Cc;
        float4 a = *reinterpret_cast<const float4*>(&E1[lane * 8]);
        float4 c = *reinterpret_cast<const float4*>(&E1[lane * 8 + 4]);
        v[0] = a.x; v[1] = a.y; v[2] = a.z; v[3] = a.w;
        v[4] = c.x; v[5] = c.y; v[6] = c.z; v[7] = c.w;
    }
#pragma unroll
    for (int p = 1; p < HALVES; ++p) {
        const float* E2 = eA + p * NE + (size_t)row * Cc;
        float4 a = *reinterpret_cast<const float4*>(&E2[lane * 8]);
        float4 c = *reinterpret_cast<const float4*>(&E2[lane * 8 + 4]);
        v[0] += a.x; v[1] += a.y; v[2] += a.z; v[3] += a.w;
        v[4] += c.x; v[5] += c.y; v[6] += c.z; v[7] += c.w;
    }
    float mn = v[0];
#pragma unroll
    for (int i = 1; i < 8; ++i) mn = fminf(mn, v[i]);
#pragma unroll
    for (int off = 32; off; off >>= 1) mn = fminf(mn, __shfl_xor(mn, off, 64));
    float sum = 0.f;
#pragma unroll
    for (int i = 0; i < 8; ++i) {
        v[i] = __expf(mn - v[i]);
        sum += v[i];
    }
#pragma unroll
    for (int off = 32; off; off >>= 1) sum += __shfl_xor(sum, off, 64);
    const float inv = 1.0f / sum;
    half8 h;
#pragma unroll
    for (int i = 0; i < 8; ++i) h[i] = (_Float16)(v[i] * inv);
    *reinterpret_cast<half8*>(&attH[(size_t)row * Cc + lane * 8]) = h;
}

// ===========================================================================
// Fallback fp32 path (known good) for small workspace.
#define TILE 64
#define KT 32
#define PAD 68

__global__ __launch_bounds__(256) void gram_f32(const float* __restrict__ x,
                                                float* __restrict__ energy) {
    __shared__ __align__(16) float As[KT][PAD];
    __shared__ __align__(16) float Bs[KT][PAD];
    const int b = blockIdx.z;
    const int rowTile = blockIdx.y * TILE;
    const int colTile = blockIdx.x * TILE;
    const float* Q = x + (size_t)b * Cc * NN;
    const int t = threadIdx.x;
    const int tx = t & 15;
    const int ty = t >> 4;
    float acc[4][4] = {};
    for (int k0 = 0; k0 < NN; k0 += KT) {
#pragma unroll
        for (int i = 0; i < 8; ++i) {
            int idx = t + i * 256;
            int r = idx >> 5;
            int k = idx & 31;
            As[k][r] = Q[(size_t)(rowTile + r) * NN + k0 + k];
            Bs[k][r] = Q[(size_t)(colTile + r) * NN + k0 + k];
        }
        __syncthreads();
#pragma unroll
        for (int k = 0; k < KT; ++k) {
            float4 a = *reinterpret_cast<const float4*>(&As[k][ty * 4]);
            float4 bq = *reinterpret_cast<const float4*>(&Bs[k][tx * 4]);
            float av[4] = {a.x, a.y, a.z, a.w};
            float bv[4] = {bq.x, bq.y, bq.z, bq.w};
#pragma unroll
            for (int i = 0; i < 4; ++i)
#pragma unroll
                for (int j = 0; j < 4; ++j)
                    acc[i][j] = fmaf(av[i], bv[j], acc[i][j]);
        }
        __syncthreads();
    }
    float* E = energy + (size_t)b * Cc * Cc;
#pragma unroll
    for (int i = 0; i < 4; ++i) {
        const int rowG = rowTile + ty * 4 + i;
        float4 o;
        o.x = acc[i][0]; o.y = acc[i][1]; o.z = acc[i][2]; o.w = acc[i][3];
        *reinterpret_cast<float4*>(&E[(size_t)rowG * Cc + colTile + tx * 4]) = o;
    }
}

__global__ __launch_bounds__(256) void softmax_f32(float* __restrict__ energy) {
    const int wave = threadIdx.x >> 6;
    const int lane = threadIdx.x & 63;
    const int row = blockIdx.x * 4 + wave;
    float* E = energy + (size_t)row * Cc;
    float v[8];
    float mn = 3.4e38f;
#pragma unroll
    for (int i = 0; i < 8; ++i) {
        v[i] = E[lane + 64 * i];
        mn = fminf(mn, v[i]);
    }
#pragma unroll
    for (int off = 32; off; off >>= 1) mn = fminf(mn, __shfl_xor(mn, off, 64));
    float sum = 0.f;
#pragma unroll
    for (int i = 0; i < 8; ++i) {
        v[i] = __expf(mn - v[i]);
        sum += v[i];
    }
#pragma unroll
    for (int off = 32; off; off >>= 1) sum += __shfl_xor(sum, off, 64);
    const float inv = 1.0f / sum;
#pragma unroll
    for (int i = 0; i < 8; ++i) E[lane + 64 * i] = v[i] * inv;
}

__global__ __launch_bounds__(256) void pv_f32(const float* __restrict__ x,
                                              const float* __restrict__ att,
                                              const float* __restrict__ gamma,
                                              float* __restrict__ out) {
    __shared__ __align__(16) float As[KT][PAD];
    __shared__ __align__(16) float Bs[KT][PAD];
    const int b = blockIdx.z;
    const int rowTile = blockIdx.y * TILE;
    const int colTile = blockIdx.x * TILE;
    const float* Q = x + (size_t)b * Cc * NN;
    const float* A = att + (size_t)b * Cc * Cc;
    const int t = threadIdx.x;
    const int tx = t & 15;
    const int ty = t >> 4;
    float acc[4][4] = {};
    for (int k0 = 0; k0 < Cc; k0 += KT) {
#pragma unroll
        for (int i = 0; i < 8; ++i) {
            int idx = t + i * 256;
            {
                int r = idx >> 5, k = idx & 31;
                As[k][r] = A[(size_t)(rowTile + r) * Cc + k0 + k];
            }
            {
                int k = idx >> 6, c = idx & 63;
                Bs[k][c] = Q[(size_t)(k0 + k) * NN + colTile + c];
            }
        }
        __syncthreads();
#pragma unroll
        for (int k = 0; k < KT; ++k) {
            float4 a = *reinterpret_cast<const float4*>(&As[k][ty * 4]);
            float4 bq = *reinterpret_cast<const float4*>(&Bs[k][tx * 4]);
            float av[4] = {a.x, a.y, a.z, a.w};
            float bv[4] = {bq.x, bq.y, bq.z, bq.w};
#pragma unroll
            for (int i = 0; i < 4; ++i)
#pragma unroll
                for (int j = 0; j < 4; ++j)
                    acc[i][j] = fmaf(av[i], bv[j], acc[i][j]);
        }
        __syncthreads();
    }
    const float g = gamma[0];
#pragma unroll
    for (int i = 0; i < 4; ++i) {
        const int rowG = rowTile + ty * 4 + i;
        const size_t base = (size_t)rowG * NN + colTile + tx * 4;
        const float4 xi = *reinterpret_cast<const float4*>(&Q[base]);
        float4 o;
        o.x = fmaf(g, acc[i][0], xi.x);
        o.y = fmaf(g, acc[i][1], xi.y);
        o.z = fmaf(g, acc[i][2], xi.z);
        o.w = fmaf(g, acc[i][3], xi.w);
        *reinterpret_cast<float4*>(&out[(size_t)b * Cc * NN + base]) = o;
    }
}

// ===========================================================================
extern "C" void kernel_launch(void* const* d_in, const int* in_sizes, int n_in,
                              void* d_out, int out_size, void* d_ws, size_t ws_size,
                              hipStream_t stream) {
    const float* x = (const float*)d_in[0];
    const float* gamma = (const float*)d_in[1];
    float* out = (float*)d_out;

    const size_t NQ = (size_t)Bb * Cc * NN;   // 33,554,432 elems
    const size_t NE = (size_t)Bb * Cc * Cc;   // 4,194,304 elems
    const size_t NEED1 = NQ * 4 + NE * 4 + NE * 2;      // 159,383,552 B
    const size_t NEED2 = NQ * 4 + NE * 8 + NE * 2;      // 176,160,768 B
    const size_t NEED4 = NQ * 4 + NE * 16 + NE * 2;     // 209,715,200 B

    if (ws_size >= NEED1) {
        _Float16* Qh = (_Float16*)d_ws;
        _Float16* QhT = Qh + NQ;
        float* eA = (float*)(QhT + NQ);
        if (ws_size >= NEED4) {
            _Float16* attH = (_Float16*)(eA + 4 * NE);
            prep_kernel<<<dim3(NN / 64, Cc / 64, Bb), 256, 0, stream>>>(x, Qh, QhT);
            gram_sym<4><<<dim3(40 * Bb), 512, 0, stream>>>(Qh, eA);
            softmax_fp16<4><<<dim3(Bb * Cc / 4), 256, 0, stream>>>(eA, attH);
            pv_mfma<1><<<dim3(128 * Bb), 512, 0, stream>>>(attH, QhT, x, Qh, gamma, out);
        } else if (ws_size >= NEED2) {
            _Float16* attH = (_Float16*)(eA + 2 * NE);
            prep_kernel<<<dim3(NN / 64, Cc / 64, Bb), 256, 0, stream>>>(x, Qh, QhT);
            gram_sym<2><<<dim3(20 * Bb), 512, 0, stream>>>(Qh, eA);
            softmax_fp16<2><<<dim3(Bb * Cc / 4), 256, 0, stream>>>(eA, attH);
            pv_mfma<1><<<dim3(128 * Bb), 512, 0, stream>>>(attH, QhT, x, Qh, gamma, out);
        } else {
            _Float16* attH = (_Float16*)(eA + NE);
            prep_kernel<<<dim3(NN / 64, Cc / 64, Bb), 256, 0, stream>>>(x, Qh, QhT);
            gram_sym<1><<<dim3(10 * Bb), 512, 0, stream>>>(Qh, eA);
            softmax_fp16<1><<<dim3(Bb * Cc / 4), 256, 0, stream>>>(eA, attH);
            pv_mfma<1><<<dim3(128 * Bb), 512, 0, stream>>>(attH, QhT, x, Qh, gamma, out);
        }
    } else {
        float* energy = (float*)d_ws;
        gram_f32<<<dim3(Cc / TILE, Cc / TILE, Bb), 256, 0, stream>>>(x, energy);
        softmax_f32<<<dim3(Bb * Cc / 4), 256, 0, stream>>>(energy);
        pv_f32<<<dim3(NN / TILE, Cc / TILE, Bb), 256, 0, stream>>>(x, energy, gamma, out);
    }
}

// Round 10
// 166.294 us; speedup vs baseline: 1.1971x; 1.1971x over previous
//
#include <hip/hip_runtime.h>

// CAM (channel attention): x [16,512,64,64] fp32, gamma scalar.
// energy[b] = Q Q^T; att = softmax(rowmax - energy) == exp(rowmin-e)/sum;
// out = gamma*(att@Q) + x.
// Fast path: fp16 MFMA GEMMs.
//   gram: symmetric (10 of 16 tiles, mirrored via LDS transpose), 128x128,
//         BK=64, K-split by ws tier, r3-proven 2-phase loop (r8 config).
//   pv:   128x128, BK=32, A 2-buf + B 3-buf = 40 KB LDS, counted vmcnt(1),
//         setprio, __launch_bounds__(512,6) -> 3 blocks/CU, VGPR cap 85
//         (r9's (512,8) capped VGPR at 64 -> spill -> regression).
// Stage-side XOR swizzle (BK=64 rows: c^(r&7); BK=32 rows: c^((r>>1)&3)),
// XCD-aware bijective block swizzle. Fallback: fp32 path.

constexpr int Bb = 16;
constexpr int Cc = 512;
constexpr int NN = 4096;  // 64*64

typedef _Float16 half8 __attribute__((ext_vector_type(8)));
typedef _Float16 half4 __attribute__((ext_vector_type(4)));
typedef float float4v __attribute__((ext_vector_type(4)));

// ---------------------------------------------------------------------------
__device__ inline void gld_lds16(const _Float16* g, _Float16* l) {
    __builtin_amdgcn_global_load_lds(
        (const __attribute__((address_space(1))) unsigned int*)g,
        (__attribute__((address_space(3))) unsigned int*)l, 16, 0, 0);
}

// ---------------------------------------------------------------------------
// Prep: x fp32 [b][512 d][4096 n] -> Qh fp16 [b][d][n] and QhT fp16 [b][n][d].
__global__ __launch_bounds__(256) void prep_kernel(const float* __restrict__ x,
                                                   _Float16* __restrict__ Qh,
                                                   _Float16* __restrict__ QhT) {
    __shared__ float T[64][65];
    const int b = blockIdx.z;
    const int n0 = blockIdx.x * 64;
    const int d0 = blockIdx.y * 64;
    const float* xb = x + ((size_t)b * Cc + d0) * NN + n0;
    const int tid = threadIdx.x;
#pragma unroll
    for (int i = 0; i < 4; ++i) {
        int lin = tid + i * 256;
        int dr = lin >> 4;
        int c4 = (lin & 15) * 4;
        float4 v = *reinterpret_cast<const float4*>(&xb[(size_t)dr * NN + c4]);
        T[dr][c4 + 0] = v.x; T[dr][c4 + 1] = v.y;
        T[dr][c4 + 2] = v.z; T[dr][c4 + 3] = v.w;
    }
    __syncthreads();
#pragma unroll
    for (int i = 0; i < 2; ++i) {
        int widx = tid + i * 256;
        int dr = widx >> 3;
        int cn = widx & 7;
        half8 h;
#pragma unroll
        for (int j = 0; j < 8; ++j) h[j] = (_Float16)T[dr][cn * 8 + j];
        size_t dst = ((size_t)b * Cc + d0 + dr) * NN + n0 + cn * 8;
        *reinterpret_cast<half8*>(&Qh[dst]) = h;
    }
#pragma unroll
    for (int i = 0; i < 2; ++i) {
        int widx = tid + i * 256;
        int nr = widx >> 3;
        int cd = widx & 7;
        half8 h;
#pragma unroll
        for (int j = 0; j < 8; ++j) h[j] = (_Float16)T[cd * 8 + j][nr];
        size_t dst = ((size_t)b * NN + n0 + nr) * Cc + d0 + cd * 8;
        *reinterpret_cast<half8*>(&QhT[dst]) = h;
    }
}

// ---------------------------------------------------------------------------
// Symmetric gram (r8 config): energy = Qh Qh^T, upper-triangle tiles (10 of
// 16), mirror via padded-LDS transpose. 128x128, BK=64, 8 waves, 2-buffer,
// K-split SPLIT (partials to D + half*Bb*Cc*Cc). Grid = 10*SPLIT*Bb.
template <int NT, int SPLIT>
__global__ __launch_bounds__(512, 4) void gram_sym(const _Float16* __restrict__ A,
                                                   float* __restrict__ D) {
    __shared__ __align__(16) float gL[128 * 129];  // 66,048 B; aliases staging
    _Float16* sAB = (_Float16*)gL;                 // sA[2]|sB[2], 65,536 B
    const int BPB = 10 * SPLIT;
    const int L = blockIdx.x;
    const int t0 = (L & 7) * ((BPB * Bb) >> 3) + (L >> 3);
    const int b = t0 / BPB;
    const int rem = t0 % BPB;
    const int ti = rem / SPLIT;
    const int half = rem % SPLIT;
    const int kBase = half * NT * 64;
    float* Deff = D + (size_t)half * Bb * Cc * Cc;
    int tr, tc;
    if (ti < 4)      { tr = 0; tc = ti; }
    else if (ti < 7) { tr = 1; tc = ti - 3; }
    else if (ti < 9) { tr = 2; tc = ti - 5; }
    else             { tr = 3; tc = 3; }
    const int rowTile = tr * 128;
    const int colTile = tc * 128;

    const _Float16* Ab = A + (size_t)b * Cc * NN;
    const int tid = threadIdx.x;

    float4v acc[4][2];
#pragma unroll
    for (int m = 0; m < 4; ++m)
#pragma unroll
        for (int n = 0; n < 2; ++n) acc[m][n] = (float4v){0.f, 0.f, 0.f, 0.f};

    auto stage = [&](int buf, int kt) {
        const int k0 = kBase + (kt << 6);
        _Float16* sA = sAB + buf * 8192;
        _Float16* sB = sAB + 16384 + buf * 8192;
#pragma unroll
        for (int i = 0; i < 2; ++i) {
            int idx = tid + i * 512;
            int r = idx >> 3;
            int c = idx & 7;
            int cs = (c ^ (r & 7)) << 3;
            gld_lds16(Ab + (size_t)(rowTile + r) * NN + k0 + cs, sA + idx * 8);
            gld_lds16(Ab + (size_t)(colTile + r) * NN + k0 + cs, sB + idx * 8);
        }
    };

    stage(0, 0);
    __syncthreads();

    const int wid = tid >> 6, lane = tid & 63;
    const int wr = wid >> 2, wc = wid & 3;   // 2 x 4 waves, each 64(m) x 32(n)
    const int lr = lane & 15, q = lane >> 4;

    for (int t = 0; t < NT; ++t) {
        if (t + 1 < NT) stage((t + 1) & 1, t + 1);
        const _Float16* cA = sAB + (t & 1) * 8192;
        const _Float16* cB = sAB + 16384 + (t & 1) * 8192;
#pragma unroll
        for (int s = 0; s < 2; ++s) {
            half8 af[4], bf[2];
#pragma unroll
            for (int m = 0; m < 4; ++m) {
                int r = wr * 64 + m * 16 + lr;
                int c = (s * 4 + q) ^ (r & 7);
                af[m] = *reinterpret_cast<const half8*>(&cA[r * 64 + c * 8]);
            }
#pragma unroll
            for (int n = 0; n < 2; ++n) {
                int r = wc * 32 + n * 16 + lr;
                int c = (s * 4 + q) ^ (r & 7);
                bf[n] = *reinterpret_cast<const half8*>(&cB[r * 64 + c * 8]);
            }
#pragma unroll
            for (int m = 0; m < 4; ++m)
#pragma unroll
                for (int n = 0; n < 2; ++n)
                    acc[m][n] = __builtin_amdgcn_mfma_f32_16x16x32_f16(af[m], bf[n], acc[m][n], 0, 0, 0);
        }
        __syncthreads();
    }

    // Epilogue: acc -> padded LDS, coalesced write (+ mirrored write).
    __syncthreads();
#pragma unroll
    for (int m = 0; m < 4; ++m)
#pragma unroll
        for (int n = 0; n < 2; ++n)
#pragma unroll
            for (int e = 0; e < 4; ++e)
                gL[(wr * 64 + m * 16 + q * 4 + e) * 129 + wc * 32 + n * 16 + lr] = acc[m][n][e];
    __syncthreads();

    float* Db = Deff + (size_t)b * Cc * Cc;
#pragma unroll
    for (int k = 0; k < 8; ++k) {
        int c = tid + k * 512;
        int row = c >> 5;
        int col = (c & 31) << 2;
        float4 v = *reinterpret_cast<const float4*>(&gL[row * 129 + col]);
        *reinterpret_cast<float4*>(&Db[(size_t)(rowTile + row) * Cc + colTile + col]) = v;
    }
    if (tr != tc) {
#pragma unroll
        for (int k = 0; k < 8; ++k) {
            int c = tid + k * 512;
            int crow = c >> 5;
            int r4 = (c & 31) << 2;
            float4 v;
            v.x = gL[(r4 + 0) * 129 + crow];
            v.y = gL[(r4 + 1) * 129 + crow];
            v.z = gL[(r4 + 2) * 129 + crow];
            v.w = gL[(r4 + 3) * 129 + crow];
            *reinterpret_cast<float4*>(&Db[(size_t)(colTile + crow) * Cc + rowTile + r4]) = v;
        }
    }
}

// ---------------------------------------------------------------------------
// PV: out = gamma*(attH @ QhT^T) + residual. 128x128 tile, BK=32, 8 waves.
// A 2-buf + B 3-buf = 40 KB; __launch_bounds__(512,6) -> 3 blocks/CU with
// VGPR cap 85 (no spill). Counted vmcnt(1) steady state.
// RES=0: residual from x (fp32); RES=1: residual from Qh (fp16).
template <int RES>
__global__ __launch_bounds__(512, 6) void pv_mfma(const _Float16* __restrict__ A,
                                                  const _Float16* __restrict__ Bp,
                                                  const float* __restrict__ xres,
                                                  const _Float16* __restrict__ Qh,
                                                  const float* __restrict__ gamma,
                                                  float* __restrict__ out) {
    __shared__ __align__(16) _Float16 smem[5 * 4096];  // sA[2]|sB[3] = 40 KB
    float* L = (float*)smem;                           // epilogue view 33792 B
    const int BPB = 128;
    const int Lb = blockIdx.x;
    const int t0 = (Lb & 7) * ((BPB * Bb) >> 3) + (Lb >> 3);
    const int b = t0 / BPB;
    const int rem = t0 % BPB;
    const int rowTile = (rem & 3) * 128;   // attH row panel (L2-hot)
    const int colTile = (rem >> 2) * 128;  // QhT panel (compulsory-only)

    const _Float16* Ab = A + (size_t)b * Cc * Cc;    // attH [512][512]
    const _Float16* Bbp = Bp + (size_t)b * NN * Cc;  // QhT  [4096][512]
    const int tid = threadIdx.x;

    float4v acc[4][2];
#pragma unroll
    for (int m = 0; m < 4; ++m)
#pragma unroll
        for (int n = 0; n < 2; ++n) acc[m][n] = (float4v){0.f, 0.f, 0.f, 0.f};

    // 1 load/lane per stage call (vmcnt ledger unit = 1).
    auto stageA = [&](_Float16* dst, int kt) {
        const int k0 = kt << 5;
        int r = tid >> 2, c = tid & 3;
        int cs = (c ^ ((r >> 1) & 3)) << 3;
        gld_lds16(Ab + (size_t)(rowTile + r) * Cc + k0 + cs, dst + tid * 8);
    };
    auto stageB = [&](_Float16* dst, int kt) {
        const int k0 = kt << 5;
        int r = tid >> 2, c = tid & 3;
        int cs = (c ^ ((r >> 1) & 3)) << 3;
        gld_lds16(Bbp + (size_t)(colTile + r) * Cc + k0 + cs, dst + tid * 8);
    };

    _Float16* sA0 = smem;
    _Float16* sA1 = smem + 4096;
    _Float16* sB_ = smem + 8192;  // 3 x 4096

    // Prologue queue: [A0(1), B0(1), B1(1)]
    stageA(sA0, 0);
    stageB(sB_, 0);
    stageB(sB_ + 4096, 1);

    const int wid = tid >> 6, lane = tid & 63;
    const int wr = wid >> 2, wc = wid & 3;   // 2 x 4 waves, each 64(m) x 32(n)
    const int lr = lane & 15, q = lane >> 4;

#pragma unroll
    for (int t = 0; t < 16; ++t) {
        // Need A(t),B(t) done; newest allowed in flight = B(t+1).
        if (t < 15) asm volatile("s_waitcnt vmcnt(1)" ::: "memory");
        else        asm volatile("s_waitcnt vmcnt(0)" ::: "memory");
        __builtin_amdgcn_s_barrier();
        __builtin_amdgcn_sched_barrier(0);

        const _Float16* cA = (t & 1) ? sA1 : sA0;
        const _Float16* cB = sB_ + (t % 3) * 4096;
        half8 af[4], bf[2];
#pragma unroll
        for (int m = 0; m < 4; ++m) {
            int r = wr * 64 + m * 16 + lr;
            int c = q ^ ((r >> 1) & 3);
            af[m] = *reinterpret_cast<const half8*>(&cA[r * 32 + c * 8]);
        }
#pragma unroll
        for (int n = 0; n < 2; ++n) {
            int r = wc * 32 + n * 16 + lr;
            int c = q ^ ((r >> 1) & 3);
            bf[n] = *reinterpret_cast<const half8*>(&cB[r * 32 + c * 8]);
        }
        if (t + 1 < 16) stageA((t & 1) ? sA0 : sA1, t + 1);
        if (t + 2 < 16) stageB(sB_ + ((t + 2) % 3) * 4096, t + 2);

        __builtin_amdgcn_s_setprio(1);
#pragma unroll
        for (int m = 0; m < 4; ++m)
#pragma unroll
            for (int n = 0; n < 2; ++n)
                acc[m][n] = __builtin_amdgcn_mfma_f32_16x16x32_f16(af[m], bf[n], acc[m][n], 0, 0, 0);
        __builtin_amdgcn_s_setprio(0);
    }

    // Epilogue: two 64-row half-passes through padded LDS, residual + store.
    const float g = gamma[0];
    const size_t base = (size_t)b * Cc * NN;
#pragma unroll
    for (int h = 0; h < 2; ++h) {
        __syncthreads();
        if (wr == h) {
#pragma unroll
            for (int m = 0; m < 4; ++m)
#pragma unroll
                for (int n = 0; n < 2; ++n)
#pragma unroll
                    for (int e = 0; e < 4; ++e)
                        L[(m * 16 + q * 4 + e) * 132 + wc * 32 + n * 16 + lr] = acc[m][n][e];
        }
        __syncthreads();
#pragma unroll
        for (int k = 0; k < 4; ++k) {
            int c2 = tid + k * 512;
            int row = c2 >> 5;
            int col = (c2 & 31) << 2;
            float4 v = *reinterpret_cast<const float4*>(&L[row * 132 + col]);
            size_t o = base + (size_t)(rowTile + h * 64 + row) * NN + colTile + col;
            float4 ov;
            if (RES == 0) {
                float4 xi = *reinterpret_cast<const float4*>(&xres[o]);
                ov.x = fmaf(g, v.x, xi.x); ov.y = fmaf(g, v.y, xi.y);
                ov.z = fmaf(g, v.z, xi.z); ov.w = fmaf(g, v.w, xi.w);
            } else {
                half4 hq = *reinterpret_cast<const half4*>(&Qh[o]);
                ov.x = fmaf(g, v.x, (float)hq[0]); ov.y = fmaf(g, v.y, (float)hq[1]);
                ov.z = fmaf(g, v.z, (float)hq[2]); ov.w = fmaf(g, v.w, (float)hq[3]);
            }
            *reinterpret_cast<float4*>(&out[o]) = ov;
        }
    }
}

// ---------------------------------------------------------------------------
// Softmax: att = exp(rowmin - e)/sum; energy in (1 or 2 partial buffers),
// fp16 att out (plain row-major).
template <int HALVES>
__global__ __launch_bounds__(256) void softmax_fp16(const float* __restrict__ eA,
                                                    const float* __restrict__ eB,
                                                    _Float16* __restrict__ attH) {
    const int wave = threadIdx.x >> 6;
    const int lane = threadIdx.x & 63;
    const int row = blockIdx.x * 4 + wave;
    const float* E1 = eA + (size_t)row * Cc;
    float v[8];
    {
        float4 a = *reinterpret_cast<const float4*>(&E1[lane * 8]);
        float4 c = *reinterpret_cast<const float4*>(&E1[lane * 8 + 4]);
        v[0] = a.x; v[1] = a.y; v[2] = a.z; v[3] = a.w;
        v[4] = c.x; v[5] = c.y; v[6] = c.z; v[7] = c.w;
    }
    if (HALVES == 2) {
        const float* E2 = eB + (size_t)row * Cc;
        float4 a = *reinterpret_cast<const float4*>(&E2[lane * 8]);
        float4 c = *reinterpret_cast<const float4*>(&E2[lane * 8 + 4]);
        v[0] += a.x; v[1] += a.y; v[2] += a.z; v[3] += a.w;
        v[4] += c.x; v[5] += c.y; v[6] += c.z; v[7] += c.w;
    }
    float mn = v[0];
#pragma unroll
    for (int i = 1; i < 8; ++i) mn = fminf(mn, v[i]);
#pragma unroll
    for (int off = 32; off; off >>= 1) mn = fminf(mn, __shfl_xor(mn, off, 64));
    float sum = 0.f;
#pragma unroll
    for (int i = 0; i < 8; ++i) {
        v[i] = __expf(mn - v[i]);
        sum += v[i];
    }
#pragma unroll
    for (int off = 32; off; off >>= 1) sum += __shfl_xor(sum, off, 64);
    const float inv = 1.0f / sum;
    half8 h;
#pragma unroll
    for (int i = 0; i < 8; ++i) h[i] = (_Float16)(v[i] * inv);
    *reinterpret_cast<half8*>(&attH[(size_t)row * Cc + lane * 8]) = h;
}

// ===========================================================================
// Fallback fp32 path (known good) for small workspace.
#define TILE 64
#define KT 32
#define PAD 68

__global__ __launch_bounds__(256) void gram_f32(const float* __restrict__ x,
                                                float* __restrict__ energy) {
    __shared__ __align__(16) float As[KT][PAD];
    __shared__ __align__(16) float Bs[KT][PAD];
    const int b = blockIdx.z;
    const int rowTile = blockIdx.y * TILE;
    const int colTile = blockIdx.x * TILE;
    const float* Q = x + (size_t)b * Cc * NN;
    const int t = threadIdx.x;
    const int tx = t & 15;
    const int ty = t >> 4;
    float acc[4][4] = {};
    for (int k0 = 0; k0 < NN; k0 += KT) {
#pragma unroll
        for (int i = 0; i < 8; ++i) {
            int idx = t + i * 256;
            int r = idx >> 5;
            int k = idx & 31;
            As[k][r] = Q[(size_t)(rowTile + r) * NN + k0 + k];
            Bs[k][r] = Q[(size_t)(colTile + r) * NN + k0 + k];
        }
        __syncthreads();
#pragma unroll
        for (int k = 0; k < KT; ++k) {
            float4 a = *reinterpret_cast<const float4*>(&As[k][ty * 4]);
            float4 bq = *reinterpret_cast<const float4*>(&Bs[k][tx * 4]);
            float av[4] = {a.x, a.y, a.z, a.w};
            float bv[4] = {bq.x, bq.y, bq.z, bq.w};
#pragma unroll
            for (int i = 0; i < 4; ++i)
#pragma unroll
                for (int j = 0; j < 4; ++j)
                    acc[i][j] = fmaf(av[i], bv[j], acc[i][j]);
        }
        __syncthreads();
    }
    float* E = energy + (size_t)b * Cc * Cc;
#pragma unroll
    for (int i = 0; i < 4; ++i) {
        const int rowG = rowTile + ty * 4 + i;
        float4 o;
        o.x = acc[i][0]; o.y = acc[i][1]; o.z = acc[i][2]; o.w = acc[i][3];
        *reinterpret_cast<float4*>(&E[(size_t)rowG * Cc + colTile + tx * 4]) = o;
    }
}

__global__ __launch_bounds__(256) void softmax_f32(float* __restrict__ energy) {
    const int wave = threadIdx.x >> 6;
    const int lane = threadIdx.x & 63;
    const int row = blockIdx.x * 4 + wave;
    float* E = energy + (size_t)row * Cc;
    float v[8];
    float mn = 3.4e38f;
#pragma unroll
    for (int i = 0; i < 8; ++i) {
        v[i] = E[lane + 64 * i];
        mn = fminf(mn, v[i]);
    }
#pragma unroll
    for (int off = 32; off; off >>= 1) mn = fminf(mn, __shfl_xor(mn, off, 64));
    float sum = 0.f;
#pragma unroll
    for (int i = 0; i < 8; ++i) {
        v[i] = __expf(mn - v[i]);
        sum += v[i];
    }
#pragma unroll
    for (int off = 32; off; off >>= 1) sum += __shfl_xor(sum, off, 64);
    const float inv = 1.0f / sum;
#pragma unroll
    for (int i = 0; i < 8; ++i) E[lane + 64 * i] = v[i] * inv;
}

__global__ __launch_bounds__(256) void pv_f32(const float* __restrict__ x,
                                              const float* __restrict__ att,
                                              const float* __restrict__ gamma,
                                              float* __restrict__ out) {
    __shared__ __align__(16) float As[KT][PAD];
    __shared__ __align__(16) float Bs[KT][PAD];
    const int b = blockIdx.z;
    const int rowTile = blockIdx.y * TILE;
    const int colTile = blockIdx.x * TILE;
    const float* Q = x + (size_t)b * Cc * NN;
    const float* A = att + (size_t)b * Cc * Cc;
    const int t = threadIdx.x;
    const int tx = t & 15;
    const int ty = t >> 4;
    float acc[4][4] = {};
    for (int k0 = 0; k0 < Cc; k0 += KT) {
#pragma unroll
        for (int i = 0; i < 8; ++i) {
            int idx = t + i * 256;
            {
                int r = idx >> 5, k = idx & 31;
                As[k][r] = A[(size_t)(rowTile + r) * Cc + k0 + k];
            }
            {
                int k = idx >> 6, c = idx & 63;
                Bs[k][c] = Q[(size_t)(k0 + k) * NN + colTile + c];
            }
        }
        __syncthreads();
#pragma unroll
        for (int k = 0; k < KT; ++k) {
            float4 a = *reinterpret_cast<const float4*>(&As[k][ty * 4]);
            float4 bq = *reinterpret_cast<const float4*>(&Bs[k][tx * 4]);
            float av[4] = {a.x, a.y, a.z, a.w};
            float bv[4] = {bq.x, bq.y, bq.z, bq.w};
#pragma unroll
            for (int i = 0; i < 4; ++i)
#pragma unroll
                for (int j = 0; j < 4; ++j)
                    acc[i][j] = fmaf(av[i], bv[j], acc[i][j]);
        }
        __syncthreads();
    }
    const float g = gamma[0];
#pragma unroll
    for (int i = 0; i < 4; ++i) {
        const int rowG = rowTile + ty * 4 + i;
        const size_t base = (size_t)rowG * NN + colTile + tx * 4;
        const float4 xi = *reinterpret_cast<const float4*>(&Q[base]);
        float4 o;
        o.x = fmaf(g, acc[i][0], xi.x);
        o.y = fmaf(g, acc[i][1], xi.y);
        o.z = fmaf(g, acc[i][2], xi.z);
        o.w = fmaf(g, acc[i][3], xi.w);
        *reinterpret_cast<float4*>(&out[(size_t)b * Cc * NN + base]) = o;
    }
}

// ===========================================================================
extern "C" void kernel_launch(void* const* d_in, const int* in_sizes, int n_in,
                              void* d_out, int out_size, void* d_ws, size_t ws_size,
                              hipStream_t stream) {
    const float* x = (const float*)d_in[0];
    const float* gamma = (const float*)d_in[1];
    float* out = (float*)d_out;

    const size_t NQ = (size_t)Bb * Cc * NN;   // 33,554,432 elems
    const size_t NE = (size_t)Bb * Cc * Cc;   // 4,194,304 elems
    const size_t NEED1 = NQ * 2 * 2 + NE * 4 + NE * 2;      // 159,383,552 B
    const size_t NEED2 = NQ * 2 * 2 + NE * 4 * 2;           // 167,772,160 B
    const size_t NEED3 = NQ * 2 * 2 + NE * 4 * 2 + NE * 2;  // 176,160,768 B

    if (ws_size >= NEED3) {
        // Tier 3: K-split sym-gram + separate attH + Qh-residual PV.
        _Float16* Qh = (_Float16*)d_ws;
        _Float16* QhT = Qh + NQ;
        float* eA = (float*)(QhT + NQ);            // eA | eB
        _Float16* attH = (_Float16*)(eA + 2 * NE);

        prep_kernel<<<dim3(NN / 64, Cc / 64, Bb), 256, 0, stream>>>(x, Qh, QhT);
        gram_sym<32, 2><<<dim3(20 * Bb), 512, 0, stream>>>(Qh, eA);
        softmax_fp16<2><<<dim3(Bb * Cc / 4), 256, 0, stream>>>(eA, eA + NE, attH);
        pv_mfma<1><<<dim3(128 * Bb), 512, 0, stream>>>(attH, QhT, x, Qh, gamma, out);
    } else if (ws_size >= NEED2) {
        // Tier 2: K-split sym-gram; attH overlays Qh -> x-residual PV.
        _Float16* Qh = (_Float16*)d_ws;
        _Float16* QhT = Qh + NQ;
        float* eA = (float*)(QhT + NQ);
        _Float16* attH = Qh;  // Qh dead after gram

        prep_kernel<<<dim3(NN / 64, Cc / 64, Bb), 256, 0, stream>>>(x, Qh, QhT);
        gram_sym<32, 2><<<dim3(20 * Bb), 512, 0, stream>>>(Qh, eA);
        softmax_fp16<2><<<dim3(Bb * Cc / 4), 256, 0, stream>>>(eA, eA + NE, attH);
        pv_mfma<0><<<dim3(128 * Bb), 512, 0, stream>>>(attH, QhT, x, nullptr, gamma, out);
    } else if (ws_size >= NEED1) {
        // Tier 1: single-pass sym-gram, separate attH, Qh-residual PV.
        _Float16* Qh = (_Float16*)d_ws;
        _Float16* QhT = Qh + NQ;
        float* energy = (float*)(QhT + NQ);
        _Float16* attH = (_Float16*)(energy + NE);

        prep_kernel<<<dim3(NN / 64, Cc / 64, Bb), 256, 0, stream>>>(x, Qh, QhT);
        gram_sym<64, 1><<<dim3(10 * Bb), 512, 0, stream>>>(Qh, energy);
        softmax_fp16<1><<<dim3(Bb * Cc / 4), 256, 0, stream>>>(energy, nullptr, attH);
        pv_mfma<1><<<dim3(128 * Bb), 512, 0, stream>>>(attH, QhT, x, Qh, gamma, out);
    } else {
        float* energy = (float*)d_ws;
        gram_f32<<<dim3(Cc / TILE, Cc / TILE, Bb), 256, 0, stream>>>(x, energy);
        softmax_f32<<<dim3(Bb * Cc / 4), 256, 0, stream>>>(energy);
        pv_f32<<<dim3(NN / TILE, Cc / TILE, Bb), 256, 0, stream>>>(x, energy, gamma, out);
    }
}

// Round 11
// 138.376 us; speedup vs baseline: 1.4386x; 1.2018x over previous
//
#include <hip/hip_runtime.h>

// CAM (channel attention): x [16,512,64,64] fp32, gamma scalar.
// energy[b] = Q Q^T; att = softmax(rowmax - energy) == exp(rowmin-e)/sum;
// out = gamma*(att@Q) + x.
// Fast path:
//   gram: fp16 MFMA, symmetric (10 of 16 tiles + LDS-transpose mirror),
//         128x128, BK=64, K-split by tier (r8-proven, 165us config).
//   pv:   FP8 e4m3 MFMA (att8 @ QhT8^T), 128x128, BK=64 (64B rows),
//         A 2-buf + B 3-buf = 40 KB LDS, counted vmcnt(1), setprio,
//         Qh fp16 residual, padded-LDS epilogue. Halves PV staged bytes
//         vs fp16 (r10 analysis: PV is aggregate-hierarchy-BW-bound).
// Swizzle: 16B chunks, c ^ ((r>>1)&3) for 64B rows (2-way max on 8B reads).
// XCD-aware bijective block swizzle. Fallback: fp32 path.

constexpr int Bb = 16;
constexpr int Cc = 512;
constexpr int NN = 4096;  // 64*64

typedef _Float16 half8 __attribute__((ext_vector_type(8)));
typedef _Float16 half4 __attribute__((ext_vector_type(4)));
typedef float float4v __attribute__((ext_vector_type(4)));

// ---------------------------------------------------------------------------
__device__ inline void gld_lds16(const _Float16* g, _Float16* l) {
    __builtin_amdgcn_global_load_lds(
        (const __attribute__((address_space(1))) unsigned int*)g,
        (__attribute__((address_space(3))) unsigned int*)l, 16, 0, 0);
}
__device__ inline void gld_lds16b(const unsigned char* g, unsigned char* l) {
    __builtin_amdgcn_global_load_lds(
        (const __attribute__((address_space(1))) unsigned int*)g,
        (__attribute__((address_space(3))) unsigned int*)l, 16, 0, 0);
}

// Pack 8 fp32 -> 8 fp8 e4m3 bytes (HW convert, RTNE+sat).
__device__ inline int2 pk_fp8x8(const float* v) {
    int lo = __builtin_amdgcn_cvt_pk_fp8_f32(v[0], v[1], 0, false);
    lo = __builtin_amdgcn_cvt_pk_fp8_f32(v[2], v[3], lo, true);
    int hi = __builtin_amdgcn_cvt_pk_fp8_f32(v[4], v[5], 0, false);
    hi = __builtin_amdgcn_cvt_pk_fp8_f32(v[6], v[7], hi, true);
    return int2{lo, hi};
}

// ---------------------------------------------------------------------------
// Prep: x fp32 [b][512 d][4096 n] -> Qh fp16 [b][d][n], QhT8 fp8 [b][n][d].
__global__ __launch_bounds__(256) void prep_kernel(const float* __restrict__ x,
                                                   _Float16* __restrict__ Qh,
                                                   unsigned char* __restrict__ QhT8) {
    __shared__ float T[64][65];
    const int b = blockIdx.z;
    const int n0 = blockIdx.x * 64;
    const int d0 = blockIdx.y * 64;
    const float* xb = x + ((size_t)b * Cc + d0) * NN + n0;
    const int tid = threadIdx.x;
#pragma unroll
    for (int i = 0; i < 4; ++i) {
        int lin = tid + i * 256;
        int dr = lin >> 4;
        int c4 = (lin & 15) * 4;
        float4 v = *reinterpret_cast<const float4*>(&xb[(size_t)dr * NN + c4]);
        T[dr][c4 + 0] = v.x; T[dr][c4 + 1] = v.y;
        T[dr][c4 + 2] = v.z; T[dr][c4 + 3] = v.w;
    }
    __syncthreads();
#pragma unroll
    for (int i = 0; i < 2; ++i) {
        int widx = tid + i * 256;
        int dr = widx >> 3;
        int cn = widx & 7;
        half8 h;
#pragma unroll
        for (int j = 0; j < 8; ++j) h[j] = (_Float16)T[dr][cn * 8 + j];
        size_t dst = ((size_t)b * Cc + d0 + dr) * NN + n0 + cn * 8;
        *reinterpret_cast<half8*>(&Qh[dst]) = h;
    }
#pragma unroll
    for (int i = 0; i < 2; ++i) {
        int widx = tid + i * 256;
        int nr = widx >> 3;
        int cd = widx & 7;
        float v[8];
#pragma unroll
        for (int j = 0; j < 8; ++j) v[j] = T[cd * 8 + j][nr];
        int2 pk = pk_fp8x8(v);
        size_t dst = ((size_t)b * NN + n0 + nr) * Cc + d0 + cd * 8;
        *reinterpret_cast<int2*>(&QhT8[dst]) = pk;
    }
}

// ---------------------------------------------------------------------------
// Symmetric gram (r8-proven): energy = Qh Qh^T, upper-triangle tiles (10 of
// 16), mirror via padded-LDS transpose. 128x128, BK=64, 8 waves, 2-buffer,
// K-split SPLIT (partials to D + half*Bb*Cc*Cc). Grid = 10*SPLIT*Bb.
template <int NT, int SPLIT>
__global__ __launch_bounds__(512, 4) void gram_sym(const _Float16* __restrict__ A,
                                                   float* __restrict__ D) {
    __shared__ __align__(16) float gL[128 * 129];  // 66,048 B; aliases staging
    _Float16* sAB = (_Float16*)gL;                 // sA[2]|sB[2], 65,536 B
    const int BPB = 10 * SPLIT;
    const int L = blockIdx.x;
    const int t0 = (L & 7) * ((BPB * Bb) >> 3) + (L >> 3);
    const int b = t0 / BPB;
    const int rem = t0 % BPB;
    const int ti = rem / SPLIT;
    const int half = rem % SPLIT;
    const int kBase = half * NT * 64;
    float* Deff = D + (size_t)half * Bb * Cc * Cc;
    int tr, tc;
    if (ti < 4)      { tr = 0; tc = ti; }
    else if (ti < 7) { tr = 1; tc = ti - 3; }
    else if (ti < 9) { tr = 2; tc = ti - 5; }
    else             { tr = 3; tc = 3; }
    const int rowTile = tr * 128;
    const int colTile = tc * 128;

    const _Float16* Ab = A + (size_t)b * Cc * NN;
    const int tid = threadIdx.x;

    float4v acc[4][2];
#pragma unroll
    for (int m = 0; m < 4; ++m)
#pragma unroll
        for (int n = 0; n < 2; ++n) acc[m][n] = (float4v){0.f, 0.f, 0.f, 0.f};

    auto stage = [&](int buf, int kt) {
        const int k0 = kBase + (kt << 6);
        _Float16* sA = sAB + buf * 8192;
        _Float16* sB = sAB + 16384 + buf * 8192;
#pragma unroll
        for (int i = 0; i < 2; ++i) {
            int idx = tid + i * 512;
            int r = idx >> 3;
            int c = idx & 7;
            int cs = (c ^ (r & 7)) << 3;
            gld_lds16(Ab + (size_t)(rowTile + r) * NN + k0 + cs, sA + idx * 8);
            gld_lds16(Ab + (size_t)(colTile + r) * NN + k0 + cs, sB + idx * 8);
        }
    };

    stage(0, 0);
    __syncthreads();

    const int wid = tid >> 6, lane = tid & 63;
    const int wr = wid >> 2, wc = wid & 3;   // 2 x 4 waves, each 64(m) x 32(n)
    const int lr = lane & 15, q = lane >> 4;

    for (int t = 0; t < NT; ++t) {
        if (t + 1 < NT) stage((t + 1) & 1, t + 1);
        const _Float16* cA = sAB + (t & 1) * 8192;
        const _Float16* cB = sAB + 16384 + (t & 1) * 8192;
#pragma unroll
        for (int s = 0; s < 2; ++s) {
            half8 af[4], bf[2];
#pragma unroll
            for (int m = 0; m < 4; ++m) {
                int r = wr * 64 + m * 16 + lr;
                int c = (s * 4 + q) ^ (r & 7);
                af[m] = *reinterpret_cast<const half8*>(&cA[r * 64 + c * 8]);
            }
#pragma unroll
            for (int n = 0; n < 2; ++n) {
                int r = wc * 32 + n * 16 + lr;
                int c = (s * 4 + q) ^ (r & 7);
                bf[n] = *reinterpret_cast<const half8*>(&cB[r * 64 + c * 8]);
            }
#pragma unroll
            for (int m = 0; m < 4; ++m)
#pragma unroll
                for (int n = 0; n < 2; ++n)
                    acc[m][n] = __builtin_amdgcn_mfma_f32_16x16x32_f16(af[m], bf[n], acc[m][n], 0, 0, 0);
        }
        __syncthreads();
    }

    // Epilogue: acc -> padded LDS, coalesced write (+ mirrored write).
    __syncthreads();
#pragma unroll
    for (int m = 0; m < 4; ++m)
#pragma unroll
        for (int n = 0; n < 2; ++n)
#pragma unroll
            for (int e = 0; e < 4; ++e)
                gL[(wr * 64 + m * 16 + q * 4 + e) * 129 + wc * 32 + n * 16 + lr] = acc[m][n][e];
    __syncthreads();

    float* Db = Deff + (size_t)b * Cc * Cc;
#pragma unroll
    for (int k = 0; k < 8; ++k) {
        int c = tid + k * 512;
        int row = c >> 5;
        int col = (c & 31) << 2;
        float4 v = *reinterpret_cast<const float4*>(&gL[row * 129 + col]);
        *reinterpret_cast<float4*>(&Db[(size_t)(rowTile + row) * Cc + colTile + col]) = v;
    }
    if (tr != tc) {
#pragma unroll
        for (int k = 0; k < 8; ++k) {
            int c = tid + k * 512;
            int crow = c >> 5;
            int r4 = (c & 31) << 2;
            float4 v;
            v.x = gL[(r4 + 0) * 129 + crow];
            v.y = gL[(r4 + 1) * 129 + crow];
            v.z = gL[(r4 + 2) * 129 + crow];
            v.w = gL[(r4 + 3) * 129 + crow];
            *reinterpret_cast<float4*>(&Db[(size_t)(colTile + crow) * Cc + rowTile + r4]) = v;
        }
    }
}

// ---------------------------------------------------------------------------
// PV fp8: out = gamma*(att8 @ QhT8^T) + Qh. 128x128 tile, BK=64 (64 B rows),
// 8 waves (2x4, each 64x32). A 2-buf + B 3-buf = 40 KB. Counted vmcnt(1),
// setprio. Frag reads are 8B (long); swizzle on 16B chunks keeps pair order.
__global__ __launch_bounds__(512, 6) void pv_fp8(const unsigned char* __restrict__ A8,
                                                 const unsigned char* __restrict__ B8,
                                                 const _Float16* __restrict__ Qh,
                                                 const float* __restrict__ gamma,
                                                 float* __restrict__ out) {
    __shared__ __align__(16) unsigned char smem[5 * 8192];  // sA[2]|sB[3] 40KB
    float* L = (float*)smem;                                // epilogue 33792 B
    const int BPB = 128;
    const int Lb = blockIdx.x;
    const int t0 = (Lb & 7) * ((BPB * Bb) >> 3) + (Lb >> 3);
    const int b = t0 / BPB;
    const int rem = t0 % BPB;
    const int rowTile = (rem & 3) * 128;   // att row panel (L2-hot)
    const int colTile = (rem >> 2) * 128;  // QhT8 panel (compulsory-only)

    const unsigned char* Ab = A8 + (size_t)b * Cc * Cc;    // att8 [512][512]B
    const unsigned char* Bbp = B8 + (size_t)b * NN * Cc;   // QhT8 [4096][512]B
    const int tid = threadIdx.x;

    float4v acc[4][2];
#pragma unroll
    for (int m = 0; m < 4; ++m)
#pragma unroll
        for (int n = 0; n < 2; ++n) acc[m][n] = (float4v){0.f, 0.f, 0.f, 0.f};

    // 1 load/lane per stage call; tile = 128 rows x 64 B = 8 KB.
    auto stageA = [&](unsigned char* dst, int kt) {
        const int k0 = kt << 6;
        int r = tid >> 2, c = tid & 3;
        int cs = (c ^ ((r >> 1) & 3)) << 4;
        gld_lds16b(Ab + (size_t)(rowTile + r) * Cc + k0 + cs, dst + tid * 16);
    };
    auto stageB = [&](unsigned char* dst, int kt) {
        const int k0 = kt << 6;
        int r = tid >> 2, c = tid & 3;
        int cs = (c ^ ((r >> 1) & 3)) << 4;
        gld_lds16b(Bbp + (size_t)(colTile + r) * Cc + k0 + cs, dst + tid * 16);
    };

    unsigned char* sA0 = smem;
    unsigned char* sA1 = smem + 8192;
    unsigned char* sB_ = smem + 16384;  // 3 x 8192

    // Prologue queue: [A0, B0, B1]
    stageA(sA0, 0);
    stageB(sB_, 0);
    stageB(sB_ + 8192, 1);

    const int wid = tid >> 6, lane = tid & 63;
    const int wr = wid >> 2, wc = wid & 3;   // 2 x 4 waves, each 64(m) x 32(n)
    const int lr = lane & 15, q = lane >> 4;

#pragma unroll
    for (int t = 0; t < 8; ++t) {
        // Need A(t),B(t) done; newest allowed outstanding = B(t+1).
        if (t < 7) asm volatile("s_waitcnt vmcnt(1)" ::: "memory");
        else       asm volatile("s_waitcnt vmcnt(0)" ::: "memory");
        __builtin_amdgcn_s_barrier();
        __builtin_amdgcn_sched_barrier(0);

        const unsigned char* cA = (t & 1) ? sA1 : sA0;
        const unsigned char* cB = sB_ + (t % 3) * 8192;
        long af[2][4];
        long bf[2][2];
#pragma unroll
        for (int s = 0; s < 2; ++s) {
            const int f = s * 4 + q;           // 8B chunk index in [0,8)
#pragma unroll
            for (int m = 0; m < 4; ++m) {
                int r = wr * 64 + m * 16 + lr;
                int byt = r * 64 + (((f >> 1) ^ ((r >> 1) & 3)) << 4) + ((f & 1) << 3);
                af[s][m] = *reinterpret_cast<const long*>(&cA[byt]);
            }
#pragma unroll
            for (int n = 0; n < 2; ++n) {
                int r = wc * 32 + n * 16 + lr;
                int byt = r * 64 + (((f >> 1) ^ ((r >> 1) & 3)) << 4) + ((f & 1) << 3);
                bf[s][n] = *reinterpret_cast<const long*>(&cB[byt]);
            }
        }
        if (t + 1 < 8) stageA((t & 1) ? sA0 : sA1, t + 1);
        if (t + 2 < 8) stageB(sB_ + ((t + 2) % 3) * 8192, t + 2);

        __builtin_amdgcn_s_setprio(1);
#pragma unroll
        for (int s = 0; s < 2; ++s)
#pragma unroll
            for (int m = 0; m < 4; ++m)
#pragma unroll
                for (int n = 0; n < 2; ++n)
                    acc[m][n] = __builtin_amdgcn_mfma_f32_16x16x32_fp8_fp8(
                        af[s][m], bf[s][n], acc[m][n], 0, 0, 0);
        __builtin_amdgcn_s_setprio(0);
    }

    // Epilogue: two 64-row half-passes through padded LDS, Qh residual.
    const float g = gamma[0];
    const size_t base = (size_t)b * Cc * NN;
#pragma unroll
    for (int h = 0; h < 2; ++h) {
        __syncthreads();
        if (wr == h) {
#pragma unroll
            for (int m = 0; m < 4; ++m)
#pragma unroll
                for (int n = 0; n < 2; ++n)
#pragma unroll
                    for (int e = 0; e < 4; ++e)
                        L[(m * 16 + q * 4 + e) * 132 + wc * 32 + n * 16 + lr] = acc[m][n][e];
        }
        __syncthreads();
#pragma unroll
        for (int k = 0; k < 4; ++k) {
            int c2 = tid + k * 512;
            int row = c2 >> 5;
            int col = (c2 & 31) << 2;
            float4 v = *reinterpret_cast<const float4*>(&L[row * 132 + col]);
            size_t o = base + (size_t)(rowTile + h * 64 + row) * NN + colTile + col;
            half4 hq = *reinterpret_cast<const half4*>(&Qh[o]);
            float4 ov;
            ov.x = fmaf(g, v.x, (float)hq[0]); ov.y = fmaf(g, v.y, (float)hq[1]);
            ov.z = fmaf(g, v.z, (float)hq[2]); ov.w = fmaf(g, v.w, (float)hq[3]);
            *reinterpret_cast<float4*>(&out[o]) = ov;
        }
    }
}

// ---------------------------------------------------------------------------
// Softmax: att = exp(rowmin - e)/sum; energy in (1 or 2 partial buffers),
// fp8 e4m3 att out (plain row-major, 512 B rows).
template <int HALVES>
__global__ __launch_bounds__(256) void softmax_fp8(const float* __restrict__ eA,
                                                   const float* __restrict__ eB,
                                                   unsigned char* __restrict__ att8) {
    const int wave = threadIdx.x >> 6;
    const int lane = threadIdx.x & 63;
    const int row = blockIdx.x * 4 + wave;
    const float* E1 = eA + (size_t)row * Cc;
    float v[8];
    {
        float4 a = *reinterpret_cast<const float4*>(&E1[lane * 8]);
        float4 c = *reinterpret_cast<const float4*>(&E1[lane * 8 + 4]);
        v[0] = a.x; v[1] = a.y; v[2] = a.z; v[3] = a.w;
        v[4] = c.x; v[5] = c.y; v[6] = c.z; v[7] = c.w;
    }
    if (HALVES == 2) {
        const float* E2 = eB + (size_t)row * Cc;
        float4 a = *reinterpret_cast<const float4*>(&E2[lane * 8]);
        float4 c = *reinterpret_cast<const float4*>(&E2[lane * 8 + 4]);
        v[0] += a.x; v[1] += a.y; v[2] += a.z; v[3] += a.w;
        v[4] += c.x; v[5] += c.y; v[6] += c.z; v[7] += c.w;
    }
    float mn = v[0];
#pragma unroll
    for (int i = 1; i < 8; ++i) mn = fminf(mn, v[i]);
#pragma unroll
    for (int off = 32; off; off >>= 1) mn = fminf(mn, __shfl_xor(mn, off, 64));
    float sum = 0.f;
#pragma unroll
    for (int i = 0; i < 8; ++i) {
        v[i] = __expf(mn - v[i]);
        sum += v[i];
    }
#pragma unroll
    for (int off = 32; off; off >>= 1) sum += __shfl_xor(sum, off, 64);
    const float inv = 1.0f / sum;
#pragma unroll
    for (int i = 0; i < 8; ++i) v[i] *= inv;
    int2 pk = pk_fp8x8(v);
    *reinterpret_cast<int2*>(&att8[(size_t)row * Cc + lane * 8]) = pk;
}

// ===========================================================================
// Fallback fp32 path (known good) for small workspace.
#define TILE 64
#define KT 32
#define PAD 68

__global__ __launch_bounds__(256) void gram_f32(const float* __restrict__ x,
                                                float* __restrict__ energy) {
    __shared__ __align__(16) float As[KT][PAD];
    __shared__ __align__(16) float Bs[KT][PAD];
    const int b = blockIdx.z;
    const int rowTile = blockIdx.y * TILE;
    const int colTile = blockIdx.x * TILE;
    const float* Q = x + (size_t)b * Cc * NN;
    const int t = threadIdx.x;
    const int tx = t & 15;
    const int ty = t >> 4;
    float acc[4][4] = {};
    for (int k0 = 0; k0 < NN; k0 += KT) {
#pragma unroll
        for (int i = 0; i < 8; ++i) {
            int idx = t + i * 256;
            int r = idx >> 5;
            int k = idx & 31;
            As[k][r] = Q[(size_t)(rowTile + r) * NN + k0 + k];
            Bs[k][r] = Q[(size_t)(colTile + r) * NN + k0 + k];
        }
        __syncthreads();
#pragma unroll
        for (int k = 0; k < KT; ++k) {
            float4 a = *reinterpret_cast<const float4*>(&As[k][ty * 4]);
            float4 bq = *reinterpret_cast<const float4*>(&Bs[k][tx * 4]);
            float av[4] = {a.x, a.y, a.z, a.w};
            float bv[4] = {bq.x, bq.y, bq.z, bq.w};
#pragma unroll
            for (int i = 0; i < 4; ++i)
#pragma unroll
                for (int j = 0; j < 4; ++j)
                    acc[i][j] = fmaf(av[i], bv[j], acc[i][j]);
        }
        __syncthreads();
    }
    float* E = energy + (size_t)b * Cc * Cc;
#pragma unroll
    for (int i = 0; i < 4; ++i) {
        const int rowG = rowTile + ty * 4 + i;
        float4 o;
        o.x = acc[i][0]; o.y = acc[i][1]; o.z = acc[i][2]; o.w = acc[i][3];
        *reinterpret_cast<float4*>(&E[(size_t)rowG * Cc + colTile + tx * 4]) = o;
    }
}

__global__ __launch_bounds__(256) void softmax_f32(float* __restrict__ energy) {
    const int wave = threadIdx.x >> 6;
    const int lane = threadIdx.x & 63;
    const int row = blockIdx.x * 4 + wave;
    float* E = energy + (size_t)row * Cc;
    float v[8];
    float mn = 3.4e38f;
#pragma unroll
    for (int i = 0; i < 8; ++i) {
        v[i] = E[lane + 64 * i];
        mn = fminf(mn, v[i]);
    }
#pragma unroll
    for (int off = 32; off; off >>= 1) mn = fminf(mn, __shfl_xor(mn, off, 64));
    float sum = 0.f;
#pragma unroll
    for (int i = 0; i < 8; ++i) {
        v[i] = __expf(mn - v[i]);
        sum += v[i];
    }
#pragma unroll
    for (int off = 32; off; off >>= 1) sum += __shfl_xor(sum, off, 64);
    const float inv = 1.0f / sum;
#pragma unroll
    for (int i = 0; i < 8; ++i) E[lane + 64 * i] = v[i] * inv;
}

__global__ __launch_bounds__(256) void pv_f32(const float* __restrict__ x,
                                              const float* __restrict__ att,
                                              const float* __restrict__ gamma,
                                              float* __restrict__ out) {
    __shared__ __align__(16) float As[KT][PAD];
    __shared__ __align__(16) float Bs[KT][PAD];
    const int b = blockIdx.z;
    const int rowTile = blockIdx.y * TILE;
    const int colTile = blockIdx.x * TILE;
    const float* Q = x + (size_t)b * Cc * NN;
    const float* A = att + (size_t)b * Cc * Cc;
    const int t = threadIdx.x;
    const int tx = t & 15;
    const int ty = t >> 4;
    float acc[4][4] = {};
    for (int k0 = 0; k0 < Cc; k0 += KT) {
#pragma unroll
        for (int i = 0; i < 8; ++i) {
            int idx = t + i * 256;
            {
                int r = idx >> 5, k = idx & 31;
                As[k][r] = A[(size_t)(rowTile + r) * Cc + k0 + k];
            }
            {
                int k = idx >> 6, c = idx & 63;
                Bs[k][c] = Q[(size_t)(k0 + k) * NN + colTile + c];
            }
        }
        __syncthreads();
#pragma unroll
        for (int k = 0; k < KT; ++k) {
            float4 a = *reinterpret_cast<const float4*>(&As[k][ty * 4]);
            float4 bq = *reinterpret_cast<const float4*>(&Bs[k][tx * 4]);
            float av[4] = {a.x, a.y, a.z, a.w};
            float bv[4] = {bq.x, bq.y, bq.z, bq.w};
#pragma unroll
            for (int i = 0; i < 4; ++i)
#pragma unroll
                for (int j = 0; j < 4; ++j)
                    acc[i][j] = fmaf(av[i], bv[j], acc[i][j]);
        }
        __syncthreads();
    }
    const float g = gamma[0];
#pragma unroll
    for (int i = 0; i < 4; ++i) {
        const int rowG = rowTile + ty * 4 + i;
        const size_t base = (size_t)rowG * NN + colTile + tx * 4;
        const float4 xi = *reinterpret_cast<const float4*>(&Q[base]);
        float4 o;
        o.x = fmaf(g, acc[i][0], xi.x);
        o.y = fmaf(g, acc[i][1], xi.y);
        o.z = fmaf(g, acc[i][2], xi.z);
        o.w = fmaf(g, acc[i][3], xi.w);
        *reinterpret_cast<float4*>(&out[(size_t)b * Cc * NN + base]) = o;
    }
}

// ===========================================================================
extern "C" void kernel_launch(void* const* d_in, const int* in_sizes, int n_in,
                              void* d_out, int out_size, void* d_ws, size_t ws_size,
                              hipStream_t stream) {
    const float* x = (const float*)d_in[0];
    const float* gamma = (const float*)d_in[1];
    float* out = (float*)d_out;

    const size_t NQ = (size_t)Bb * Cc * NN;   // 33,554,432 elems
    const size_t NE = (size_t)Bb * Cc * Cc;   // 4,194,304 elems
    // ws: Qh fp16 (2*NQ B) | QhT8 fp8 (NQ B) | eA fp32 (SPLIT*4*NE B) | att8 (NE B)
    const size_t NEED2 = 2 * NQ + NQ + 8 * NE + NE;  // 138,412,032 B (K-split x2)
    const size_t NEED1 = 2 * NQ + NQ + 4 * NE + NE;  // 121,634,816 B

    if (ws_size >= NEED1) {
        _Float16* Qh = (_Float16*)d_ws;
        unsigned char* QhT8 = (unsigned char*)(Qh + NQ);
        float* eA = (float*)(QhT8 + NQ);

        prep_kernel<<<dim3(NN / 64, Cc / 64, Bb), 256, 0, stream>>>(x, Qh, QhT8);
        if (ws_size >= NEED2) {
            unsigned char* att8 = (unsigned char*)(eA + 2 * NE);
            gram_sym<32, 2><<<dim3(20 * Bb), 512, 0, stream>>>(Qh, eA);
            softmax_fp8<2><<<dim3(Bb * Cc / 4), 256, 0, stream>>>(eA, eA + NE, att8);
            pv_fp8<<<dim3(128 * Bb), 512, 0, stream>>>(att8, QhT8, Qh, gamma, out);
        } else {
            unsigned char* att8 = (unsigned char*)(eA + NE);
            gram_sym<64, 1><<<dim3(10 * Bb), 512, 0, stream>>>(Qh, eA);
            softmax_fp8<1><<<dim3(Bb * Cc / 4), 256, 0, stream>>>(eA, nullptr, att8);
            pv_fp8<<<dim3(128 * Bb), 512, 0, stream>>>(att8, QhT8, Qh, gamma, out);
        }
    } else {
        float* energy = (float*)d_ws;
        gram_f32<<<dim3(Cc / TILE, Cc / TILE, Bb), 256, 0, stream>>>(x, energy);
        softmax_f32<<<dim3(Bb * Cc / 4), 256, 0, stream>>>(energy);
        pv_f32<<<dim3(NN / TILE, Cc / TILE, Bb), 256, 0, stream>>>(x, energy, gamma, out);
    }
}

// Round 12
// 137.800 us; speedup vs baseline: 1.4446x; 1.0042x over previous
//
#include <hip/hip_runtime.h>

// CAM (channel attention): x [16,512,64,64] fp32, gamma scalar.
// energy[b] = Q Q^T; att = softmax(rowmax - energy) == exp(rowmin-e)/sum;
// out = gamma*(att@Q) + x.
// Fast path:
//   gram: fp16 MFMA, symmetric (10 of 16 tiles + LDS-transpose mirror),
//         128x128, BK=64, K-split by tier (r8-proven).
//   pv:   FP8 e4m3 MFMA (att8 @ QhT8^T), 128x128, BK=64 (64B rows),
//         A 3-buf + B 3-buf = 48 KB LDS, counted vmcnt(2) (2-phase cover
//         for BOTH operands), setprio, Qh fp16 residual, LDS epilogue.
// Swizzle: 16B chunks, c ^ ((r>>1)&3) for 64B rows (2-way max on 8B reads).
// XCD-aware bijective block swizzle. Fallback: fp32 path.

constexpr int Bb = 16;
constexpr int Cc = 512;
constexpr int NN = 4096;  // 64*64

typedef _Float16 half8 __attribute__((ext_vector_type(8)));
typedef _Float16 half4 __attribute__((ext_vector_type(4)));
typedef float float4v __attribute__((ext_vector_type(4)));

// ---------------------------------------------------------------------------
__device__ inline void gld_lds16(const _Float16* g, _Float16* l) {
    __builtin_amdgcn_global_load_lds(
        (const __attribute__((address_space(1))) unsigned int*)g,
        (__attribute__((address_space(3))) unsigned int*)l, 16, 0, 0);
}
__device__ inline void gld_lds16b(const unsigned char* g, unsigned char* l) {
    __builtin_amdgcn_global_load_lds(
        (const __attribute__((address_space(1))) unsigned int*)g,
        (__attribute__((address_space(3))) unsigned int*)l, 16, 0, 0);
}

// Pack 8 fp32 -> 8 fp8 e4m3 bytes (HW convert, RTNE+sat).
__device__ inline int2 pk_fp8x8(const float* v) {
    int lo = __builtin_amdgcn_cvt_pk_fp8_f32(v[0], v[1], 0, false);
    lo = __builtin_amdgcn_cvt_pk_fp8_f32(v[2], v[3], lo, true);
    int hi = __builtin_amdgcn_cvt_pk_fp8_f32(v[4], v[5], 0, false);
    hi = __builtin_amdgcn_cvt_pk_fp8_f32(v[6], v[7], hi, true);
    return int2{lo, hi};
}

// ---------------------------------------------------------------------------
// Prep: x fp32 [b][512 d][4096 n] -> Qh fp16 [b][d][n], QhT8 fp8 [b][n][d].
__global__ __launch_bounds__(256) void prep_kernel(const float* __restrict__ x,
                                                   _Float16* __restrict__ Qh,
                                                   unsigned char* __restrict__ QhT8) {
    __shared__ float T[64][65];
    const int b = blockIdx.z;
    const int n0 = blockIdx.x * 64;
    const int d0 = blockIdx.y * 64;
    const float* xb = x + ((size_t)b * Cc + d0) * NN + n0;
    const int tid = threadIdx.x;
#pragma unroll
    for (int i = 0; i < 4; ++i) {
        int lin = tid + i * 256;
        int dr = lin >> 4;
        int c4 = (lin & 15) * 4;
        float4 v = *reinterpret_cast<const float4*>(&xb[(size_t)dr * NN + c4]);
        T[dr][c4 + 0] = v.x; T[dr][c4 + 1] = v.y;
        T[dr][c4 + 2] = v.z; T[dr][c4 + 3] = v.w;
    }
    __syncthreads();
#pragma unroll
    for (int i = 0; i < 2; ++i) {
        int widx = tid + i * 256;
        int dr = widx >> 3;
        int cn = widx & 7;
        half8 h;
#pragma unroll
        for (int j = 0; j < 8; ++j) h[j] = (_Float16)T[dr][cn * 8 + j];
        size_t dst = ((size_t)b * Cc + d0 + dr) * NN + n0 + cn * 8;
        *reinterpret_cast<half8*>(&Qh[dst]) = h;
    }
#pragma unroll
    for (int i = 0; i < 2; ++i) {
        int widx = tid + i * 256;
        int nr = widx >> 3;
        int cd = widx & 7;
        float v[8];
#pragma unroll
        for (int j = 0; j < 8; ++j) v[j] = T[cd * 8 + j][nr];
        int2 pk = pk_fp8x8(v);
        size_t dst = ((size_t)b * NN + n0 + nr) * Cc + d0 + cd * 8;
        *reinterpret_cast<int2*>(&QhT8[dst]) = pk;
    }
}

// ---------------------------------------------------------------------------
// Symmetric gram (r8-proven): energy = Qh Qh^T, upper-triangle tiles (10 of
// 16), mirror via padded-LDS transpose. 128x128, BK=64, 8 waves, 2-buffer,
// K-split SPLIT (partials to D + half*Bb*Cc*Cc). Grid = 10*SPLIT*Bb.
template <int NT, int SPLIT>
__global__ __launch_bounds__(512, 4) void gram_sym(const _Float16* __restrict__ A,
                                                   float* __restrict__ D) {
    __shared__ __align__(16) float gL[128 * 129];  // 66,048 B; aliases staging
    _Float16* sAB = (_Float16*)gL;                 // sA[2]|sB[2], 65,536 B
    const int BPB = 10 * SPLIT;
    const int L = blockIdx.x;
    const int t0 = (L & 7) * ((BPB * Bb) >> 3) + (L >> 3);
    const int b = t0 / BPB;
    const int rem = t0 % BPB;
    const int ti = rem / SPLIT;
    const int half = rem % SPLIT;
    const int kBase = half * NT * 64;
    float* Deff = D + (size_t)half * Bb * Cc * Cc;
    int tr, tc;
    if (ti < 4)      { tr = 0; tc = ti; }
    else if (ti < 7) { tr = 1; tc = ti - 3; }
    else if (ti < 9) { tr = 2; tc = ti - 5; }
    else             { tr = 3; tc = 3; }
    const int rowTile = tr * 128;
    const int colTile = tc * 128;

    const _Float16* Ab = A + (size_t)b * Cc * NN;
    const int tid = threadIdx.x;

    float4v acc[4][2];
#pragma unroll
    for (int m = 0; m < 4; ++m)
#pragma unroll
        for (int n = 0; n < 2; ++n) acc[m][n] = (float4v){0.f, 0.f, 0.f, 0.f};

    auto stage = [&](int buf, int kt) {
        const int k0 = kBase + (kt << 6);
        _Float16* sA = sAB + buf * 8192;
        _Float16* sB = sAB + 16384 + buf * 8192;
#pragma unroll
        for (int i = 0; i < 2; ++i) {
            int idx = tid + i * 512;
            int r = idx >> 3;
            int c = idx & 7;
            int cs = (c ^ (r & 7)) << 3;
            gld_lds16(Ab + (size_t)(rowTile + r) * NN + k0 + cs, sA + idx * 8);
            gld_lds16(Ab + (size_t)(colTile + r) * NN + k0 + cs, sB + idx * 8);
        }
    };

    stage(0, 0);
    __syncthreads();

    const int wid = tid >> 6, lane = tid & 63;
    const int wr = wid >> 2, wc = wid & 3;   // 2 x 4 waves, each 64(m) x 32(n)
    const int lr = lane & 15, q = lane >> 4;

    for (int t = 0; t < NT; ++t) {
        if (t + 1 < NT) stage((t + 1) & 1, t + 1);
        const _Float16* cA = sAB + (t & 1) * 8192;
        const _Float16* cB = sAB + 16384 + (t & 1) * 8192;
#pragma unroll
        for (int s = 0; s < 2; ++s) {
            half8 af[4], bf[2];
#pragma unroll
            for (int m = 0; m < 4; ++m) {
                int r = wr * 64 + m * 16 + lr;
                int c = (s * 4 + q) ^ (r & 7);
                af[m] = *reinterpret_cast<const half8*>(&cA[r * 64 + c * 8]);
            }
#pragma unroll
            for (int n = 0; n < 2; ++n) {
                int r = wc * 32 + n * 16 + lr;
                int c = (s * 4 + q) ^ (r & 7);
                bf[n] = *reinterpret_cast<const half8*>(&cB[r * 64 + c * 8]);
            }
#pragma unroll
            for (int m = 0; m < 4; ++m)
#pragma unroll
                for (int n = 0; n < 2; ++n)
                    acc[m][n] = __builtin_amdgcn_mfma_f32_16x16x32_f16(af[m], bf[n], acc[m][n], 0, 0, 0);
        }
        __syncthreads();
    }

    // Epilogue: acc -> padded LDS, coalesced write (+ mirrored write).
    __syncthreads();
#pragma unroll
    for (int m = 0; m < 4; ++m)
#pragma unroll
        for (int n = 0; n < 2; ++n)
#pragma unroll
            for (int e = 0; e < 4; ++e)
                gL[(wr * 64 + m * 16 + q * 4 + e) * 129 + wc * 32 + n * 16 + lr] = acc[m][n][e];
    __syncthreads();

    float* Db = Deff + (size_t)b * Cc * Cc;
#pragma unroll
    for (int k = 0; k < 8; ++k) {
        int c = tid + k * 512;
        int row = c >> 5;
        int col = (c & 31) << 2;
        float4 v = *reinterpret_cast<const float4*>(&gL[row * 129 + col]);
        *reinterpret_cast<float4*>(&Db[(size_t)(rowTile + row) * Cc + colTile + col]) = v;
    }
    if (tr != tc) {
#pragma unroll
        for (int k = 0; k < 8; ++k) {
            int c = tid + k * 512;
            int crow = c >> 5;
            int r4 = (c & 31) << 2;
            float4 v;
            v.x = gL[(r4 + 0) * 129 + crow];
            v.y = gL[(r4 + 1) * 129 + crow];
            v.z = gL[(r4 + 2) * 129 + crow];
            v.w = gL[(r4 + 3) * 129 + crow];
            *reinterpret_cast<float4*>(&Db[(size_t)(colTile + crow) * Cc + rowTile + r4]) = v;
        }
    }
}

// ---------------------------------------------------------------------------
// PV fp8: out = gamma*(att8 @ QhT8^T) + Qh. 128x128 tile, BK=64 (64 B rows),
// 8 waves (2x4, each 64x32). A 3-buf + B 3-buf = 48 KB, counted vmcnt(2)
// (tile t+1's 2 loads stay in flight; 2-phase cover), setprio.
__global__ __launch_bounds__(512, 6) void pv_fp8(const unsigned char* __restrict__ A8,
                                                 const unsigned char* __restrict__ B8,
                                                 const _Float16* __restrict__ Qh,
                                                 const float* __restrict__ gamma,
                                                 float* __restrict__ out) {
    __shared__ __align__(16) unsigned char smem[6 * 8192];  // sA[3]|sB[3] 48KB
    float* L = (float*)smem;                                // epilogue 33792 B
    const int BPB = 128;
    const int Lb = blockIdx.x;
    const int t0 = (Lb & 7) * ((BPB * Bb) >> 3) + (Lb >> 3);
    const int b = t0 / BPB;
    const int rem = t0 % BPB;
    const int rowTile = (rem & 3) * 128;   // att row panel (L2-hot)
    const int colTile = (rem >> 2) * 128;  // QhT8 panel (compulsory-only)

    const unsigned char* Ab = A8 + (size_t)b * Cc * Cc;    // att8 [512][512]B
    const unsigned char* Bbp = B8 + (size_t)b * NN * Cc;   // QhT8 [4096][512]B
    const int tid = threadIdx.x;

    float4v acc[4][2];
#pragma unroll
    for (int m = 0; m < 4; ++m)
#pragma unroll
        for (int n = 0; n < 2; ++n) acc[m][n] = (float4v){0.f, 0.f, 0.f, 0.f};

    // 1 load/lane per stage call; tile = 128 rows x 64 B = 8 KB.
    auto stageA = [&](unsigned char* dst, int kt) {
        const int k0 = kt << 6;
        int r = tid >> 2, c = tid & 3;
        int cs = (c ^ ((r >> 1) & 3)) << 4;
        gld_lds16b(Ab + (size_t)(rowTile + r) * Cc + k0 + cs, dst + tid * 16);
    };
    auto stageB = [&](unsigned char* dst, int kt) {
        const int k0 = kt << 6;
        int r = tid >> 2, c = tid & 3;
        int cs = (c ^ ((r >> 1) & 3)) << 4;
        gld_lds16b(Bbp + (size_t)(colTile + r) * Cc + k0 + cs, dst + tid * 16);
    };

    unsigned char* sA_ = smem;          // 3 x 8192
    unsigned char* sB_ = smem + 24576;  // 3 x 8192

    // Prologue (tile order!): [A0,B0, A1,B1]
    stageA(sA_, 0);
    stageB(sB_, 0);
    stageA(sA_ + 8192, 1);
    stageB(sB_ + 8192, 1);

    const int wid = tid >> 6, lane = tid & 63;
    const int wr = wid >> 2, wc = wid & 3;   // 2 x 4 waves, each 64(m) x 32(n)
    const int lr = lane & 15, q = lane >> 4;

#pragma unroll
    for (int t = 0; t < 8; ++t) {
        // Need A(t),B(t) done; newer outstanding = A(t+1),B(t+1) -> vmcnt(2).
        if (t < 7) asm volatile("s_waitcnt vmcnt(2)" ::: "memory");
        else       asm volatile("s_waitcnt vmcnt(0)" ::: "memory");
        __builtin_amdgcn_s_barrier();
        __builtin_amdgcn_sched_barrier(0);

        // Prefetch tile t+2 into ring slot (t+2)%3 (consumed at t-1; all
        // waves are past the barrier above, so overwrite is WAR-safe).
        if (t + 2 < 8) {
            stageA(sA_ + ((t + 2) % 3) * 8192, t + 2);
            stageB(sB_ + ((t + 2) % 3) * 8192, t + 2);
        }

        const unsigned char* cA = sA_ + (t % 3) * 8192;
        const unsigned char* cB = sB_ + (t % 3) * 8192;
        long af[2][4];
        long bf[2][2];
#pragma unroll
        for (int s = 0; s < 2; ++s) {
            const int f = s * 4 + q;           // 8B chunk index in [0,8)
#pragma unroll
            for (int m = 0; m < 4; ++m) {
                int r = wr * 64 + m * 16 + lr;
                int byt = r * 64 + (((f >> 1) ^ ((r >> 1) & 3)) << 4) + ((f & 1) << 3);
                af[s][m] = *reinterpret_cast<const long*>(&cA[byt]);
            }
#pragma unroll
            for (int n = 0; n < 2; ++n) {
                int r = wc * 32 + n * 16 + lr;
                int byt = r * 64 + (((f >> 1) ^ ((r >> 1) & 3)) << 4) + ((f & 1) << 3);
                bf[s][n] = *reinterpret_cast<const long*>(&cB[byt]);
            }
        }

        __builtin_amdgcn_s_setprio(1);
#pragma unroll
        for (int s = 0; s < 2; ++s)
#pragma unroll
            for (int m = 0; m < 4; ++m)
#pragma unroll
                for (int n = 0; n < 2; ++n)
                    acc[m][n] = __builtin_amdgcn_mfma_f32_16x16x32_fp8_fp8(
                        af[s][m], bf[s][n], acc[m][n], 0, 0, 0);
        __builtin_amdgcn_s_setprio(0);
    }

    // Epilogue: two 64-row half-passes through padded LDS, Qh residual.
    const float g = gamma[0];
    const size_t base = (size_t)b * Cc * NN;
#pragma unroll
    for (int h = 0; h < 2; ++h) {
        __syncthreads();
        if (wr == h) {
#pragma unroll
            for (int m = 0; m < 4; ++m)
#pragma unroll
                for (int n = 0; n < 2; ++n)
#pragma unroll
                    for (int e = 0; e < 4; ++e)
                        L[(m * 16 + q * 4 + e) * 132 + wc * 32 + n * 16 + lr] = acc[m][n][e];
        }
        __syncthreads();
#pragma unroll
        for (int k = 0; k < 4; ++k) {
            int c2 = tid + k * 512;
            int row = c2 >> 5;
            int col = (c2 & 31) << 2;
            float4 v = *reinterpret_cast<const float4*>(&L[row * 132 + col]);
            size_t o = base + (size_t)(rowTile + h * 64 + row) * NN + colTile + col;
            half4 hq = *reinterpret_cast<const half4*>(&Qh[o]);
            float4 ov;
            ov.x = fmaf(g, v.x, (float)hq[0]); ov.y = fmaf(g, v.y, (float)hq[1]);
            ov.z = fmaf(g, v.z, (float)hq[2]); ov.w = fmaf(g, v.w, (float)hq[3]);
            *reinterpret_cast<float4*>(&out[o]) = ov;
        }
    }
}

// ---------------------------------------------------------------------------
// Softmax: att = exp(rowmin - e)/sum; energy in (1 or 2 partial buffers),
// fp8 e4m3 att out (plain row-major, 512 B rows).
template <int HALVES>
__global__ __launch_bounds__(256) void softmax_fp8(const float* __restrict__ eA,
                                                   const float* __restrict__ eB,
                                                   unsigned char* __restrict__ att8) {
    const int wave = threadIdx.x >> 6;
    const int lane = threadIdx.x & 63;
    const int row = blockIdx.x * 4 + wave;
    const float* E1 = eA + (size_t)row * Cc;
    float v[8];
    {
        float4 a = *reinterpret_cast<const float4*>(&E1[lane * 8]);
        float4 c = *reinterpret_cast<const float4*>(&E1[lane * 8 + 4]);
        v[0] = a.x; v[1] = a.y; v[2] = a.z; v[3] = a.w;
        v[4] = c.x; v[5] = c.y; v[6] = c.z; v[7] = c.w;
    }
    if (HALVES == 2) {
        const float* E2 = eB + (size_t)row * Cc;
        float4 a = *reinterpret_cast<const float4*>(&E2[lane * 8]);
        float4 c = *reinterpret_cast<const float4*>(&E2[lane * 8 + 4]);
        v[0] += a.x; v[1] += a.y; v[2] += a.z; v[3] += a.w;
        v[4] += c.x; v[5] += c.y; v[6] += c.z; v[7] += c.w;
    }
    float mn = v[0];
#pragma unroll
    for (int i = 1; i < 8; ++i) mn = fminf(mn, v[i]);
#pragma unroll
    for (int off = 32; off; off >>= 1) mn = fminf(mn, __shfl_xor(mn, off, 64));
    float sum = 0.f;
#pragma unroll
    for (int i = 0; i < 8; ++i) {
        v[i] = __expf(mn - v[i]);
        sum += v[i];
    }
#pragma unroll
    for (int off = 32; off; off >>= 1) sum += __shfl_xor(sum, off, 64);
    const float inv = 1.0f / sum;
#pragma unroll
    for (int i = 0; i < 8; ++i) v[i] *= inv;
    int2 pk = pk_fp8x8(v);
    *reinterpret_cast<int2*>(&att8[(size_t)row * Cc + lane * 8]) = pk;
}

// ===========================================================================
// Fallback fp32 path (known good) for small workspace.
#define TILE 64
#define KT 32
#define PAD 68

__global__ __launch_bounds__(256) void gram_f32(const float* __restrict__ x,
                                                float* __restrict__ energy) {
    __shared__ __align__(16) float As[KT][PAD];
    __shared__ __align__(16) float Bs[KT][PAD];
    const int b = blockIdx.z;
    const int rowTile = blockIdx.y * TILE;
    const int colTile = blockIdx.x * TILE;
    const float* Q = x + (size_t)b * Cc * NN;
    const int t = threadIdx.x;
    const int tx = t & 15;
    const int ty = t >> 4;
    float acc[4][4] = {};
    for (int k0 = 0; k0 < NN; k0 += KT) {
#pragma unroll
        for (int i = 0; i < 8; ++i) {
            int idx = t + i * 256;
            int r = idx >> 5;
            int k = idx & 31;
            As[k][r] = Q[(size_t)(rowTile + r) * NN + k0 + k];
            Bs[k][r] = Q[(size_t)(colTile + r) * NN + k0 + k];
        }
        __syncthreads();
#pragma unroll
        for (int k = 0; k < KT; ++k) {
            float4 a = *reinterpret_cast<const float4*>(&As[k][ty * 4]);
            float4 bq = *reinterpret_cast<const float4*>(&Bs[k][tx * 4]);
            float av[4] = {a.x, a.y, a.z, a.w};
            float bv[4] = {bq.x, bq.y, bq.z, bq.w};
#pragma unroll
            for (int i = 0; i < 4; ++i)
#pragma unroll
                for (int j = 0; j < 4; ++j)
                    acc[i][j] = fmaf(av[i], bv[j], acc[i][j]);
        }
        __syncthreads();
    }
    float* E = energy + (size_t)b * Cc * Cc;
#pragma unroll
    for (int i = 0; i < 4; ++i) {
        const int rowG = rowTile + ty * 4 + i;
        float4 o;
        o.x = acc[i][0]; o.y = acc[i][1]; o.z = acc[i][2]; o.w = acc[i][3];
        *reinterpret_cast<float4*>(&E[(size_t)rowG * Cc + colTile + tx * 4]) = o;
    }
}

__global__ __launch_bounds__(256) void softmax_f32(float* __restrict__ energy) {
    const int wave = threadIdx.x >> 6;
    const int lane = threadIdx.x & 63;
    const int row = blockIdx.x * 4 + wave;
    float* E = energy + (size_t)row * Cc;
    float v[8];
    float mn = 3.4e38f;
#pragma unroll
    for (int i = 0; i < 8; ++i) {
        v[i] = E[lane + 64 * i];
        mn = fminf(mn, v[i]);
    }
#pragma unroll
    for (int off = 32; off; off >>= 1) mn = fminf(mn, __shfl_xor(mn, off, 64));
    float sum = 0.f;
#pragma unroll
    for (int i = 0; i < 8; ++i) {
        v[i] = __expf(mn - v[i]);
        sum += v[i];
    }
#pragma unroll
    for (int off = 32; off; off >>= 1) sum += __shfl_xor(sum, off, 64);
    const float inv = 1.0f / sum;
#pragma unroll
    for (int i = 0; i < 8; ++i) E[lane + 64 * i] = v[i] * inv;
}

__global__ __launch_bounds__(256) void pv_f32(const float* __restrict__ x,
                                              const float* __restrict__ att,
                                              const float* __restrict__ gamma,
                                              float* __restrict__ out) {
    __shared__ __align__(16) float As[KT][PAD];
    __shared__ __align__(16) float Bs[KT][PAD];
    const int b = blockIdx.z;
    const int rowTile = blockIdx.y * TILE;
    const int colTile = blockIdx.x * TILE;
    const float* Q = x + (size_t)b * Cc * NN;
    const float* A = att + (size_t)b * Cc * Cc;
    const int t = threadIdx.x;
    const int tx = t & 15;
    const int ty = t >> 4;
    float acc[4][4] = {};
    for (int k0 = 0; k0 < Cc; k0 += KT) {
#pragma unroll
        for (int i = 0; i < 8; ++i) {
            int idx = t + i * 256;
            {
                int r = idx >> 5, k = idx & 31;
                As[k][r] = A[(size_t)(rowTile + r) * Cc + k0 + k];
            }
            {
                int k = idx >> 6, c = idx & 63;
                Bs[k][c] = Q[(size_t)(k0 + k) * NN + colTile + c];
            }
        }
        __syncthreads();
#pragma unroll
        for (int k = 0; k < KT; ++k) {
            float4 a = *reinterpret_cast<const float4*>(&As[k][ty * 4]);
            float4 bq = *reinterpret_cast<const float4*>(&Bs[k][tx * 4]);
            float av[4] = {a.x, a.y, a.z, a.w};
            float bv[4] = {bq.x, bq.y, bq.z, bq.w};
#pragma unroll
            for (int i = 0; i < 4; ++i)
#pragma unroll
                for (int j = 0; j < 4; ++j)
                    acc[i][j] = fmaf(av[i], bv[j], acc[i][j]);
        }
        __syncthreads();
    }
    const float g = gamma[0];
#pragma unroll
    for (int i = 0; i < 4; ++i) {
        const int rowG = rowTile + ty * 4 + i;
        const size_t base = (size_t)rowG * NN + colTile + tx * 4;
        const float4 xi = *reinterpret_cast<const float4*>(&Q[base]);
        float4 o;
        o.x = fmaf(g, acc[i][0], xi.x);
        o.y = fmaf(g, acc[i][1], xi.y);
        o.z = fmaf(g, acc[i][2], xi.z);
        o.w = fmaf(g, acc[i][3], xi.w);
        *reinterpret_cast<float4*>(&out[(size_t)b * Cc * NN + base]) = o;
    }
}

// ===========================================================================
extern "C" void kernel_launch(void* const* d_in, const int* in_sizes, int n_in,
                              void* d_out, int out_size, void* d_ws, size_t ws_size,
                              hipStream_t stream) {
    const float* x = (const float*)d_in[0];
    const float* gamma = (const float*)d_in[1];
    float* out = (float*)d_out;

    const size_t NQ = (size_t)Bb * Cc * NN;   // 33,554,432 elems
    const size_t NE = (size_t)Bb * Cc * Cc;   // 4,194,304 elems
    // ws: Qh fp16 (2*NQ B) | QhT8 fp8 (NQ B) | eA fp32 (SPLIT*4*NE B) | att8 (NE B)
    const size_t NEED2 = 2 * NQ + NQ + 8 * NE + NE;  // 138,412,032 B (K-split x2)
    const size_t NEED1 = 2 * NQ + NQ + 4 * NE + NE;  // 121,634,816 B

    if (ws_size >= NEED1) {
        _Float16* Qh = (_Float16*)d_ws;
        unsigned char* QhT8 = (unsigned char*)(Qh + NQ);
        float* eA = (float*)(QhT8 + NQ);

        prep_kernel<<<dim3(NN / 64, Cc / 64, Bb), 256, 0, stream>>>(x, Qh, QhT8);
        if (ws_size >= NEED2) {
            unsigned char* att8 = (unsigned char*)(eA + 2 * NE);
            gram_sym<32, 2><<<dim3(20 * Bb), 512, 0, stream>>>(Qh, eA);
            softmax_fp8<2><<<dim3(Bb * Cc / 4), 256, 0, stream>>>(eA, eA + NE, att8);
            pv_fp8<<<dim3(128 * Bb), 512, 0, stream>>>(att8, QhT8, Qh, gamma, out);
        } else {
            unsigned char* att8 = (unsigned char*)(eA + NE);
            gram_sym<64, 1><<<dim3(10 * Bb), 512, 0, stream>>>(Qh, eA);
            softmax_fp8<1><<<dim3(Bb * Cc / 4), 256, 0, stream>>>(eA, nullptr, att8);
            pv_fp8<<<dim3(128 * Bb), 512, 0, stream>>>(att8, QhT8, Qh, gamma, out);
        }
    } else {
        float* energy = (float*)d_ws;
        gram_f32<<<dim3(Cc / TILE, Cc / TILE, Bb), 256, 0, stream>>>(x, energy);
        softmax_f32<<<dim3(Bb * Cc / 4), 256, 0, stream>>>(energy);
        pv_f32<<<dim3(NN / TILE, Cc / TILE, Bb), 256, 0, stream>>>(x, energy, gamma, out);
    }
}